// Round 1
// baseline (444.995 us; speedup 1.0000x reference)
//
#include <hip/hip_runtime.h>
#include <hip/hip_bf16.h>
#include <math.h>

#define N_SEQ 4096
#define M_DIM 1024
#define A_DIM 128
#define H_DIM 1152

typedef __attribute__((ext_vector_type(4))) float f32x4;
typedef __attribute__((ext_vector_type(8))) short bf16x8;

__device__ inline unsigned short f2b(float f) {
  union { float f; unsigned int u; } v; v.f = f;
  unsigned int u = v.u;
  unsigned int r = (u + 0x7fffu + ((u >> 16) & 1u)) >> 16;
  return (unsigned short)r;
}

// ---------------- float -> bf16 convert (vectorized x4) ----------------
__global__ __launch_bounds__(256) void k_f2b(const float* __restrict__ src,
                                             unsigned short* __restrict__ dst, int n) {
  int base = (blockIdx.x * 256 + threadIdx.x) * 4;
  if (base + 3 < n) {
    float4 f = *reinterpret_cast<const float4*>(src + base);
    ushort4 o;
    o.x = f2b(f.x); o.y = f2b(f.y); o.z = f2b(f.z); o.w = f2b(f.w);
    *reinterpret_cast<ushort4*>(dst + base) = o;
  }
}

// ---------------- generic row LayerNorm (optional residual, f32/bf16 out) ----------------
__global__ __launch_bounds__(256) void k_ln(const float* __restrict__ src,
                                            const float* __restrict__ res,
                                            const float* __restrict__ g,
                                            const float* __restrict__ b,
                                            float* __restrict__ dstf,
                                            unsigned short* __restrict__ dstb,
                                            int D, int ostride, int ooff) {
  int i = blockIdx.x, tid = threadIdx.x, wave = tid >> 6, lane = tid & 63;
  __shared__ float rb[8];
  float v[4];
  int cnt = 0;
  float s = 0.f, ss = 0.f;
  for (int t = tid; t < D; t += 256) {
    float x = src[(size_t)i * D + t];
    if (res) x += res[(size_t)i * D + t];
    v[cnt++] = x; s += x; ss += x * x;
  }
  for (int o = 32; o; o >>= 1) { s += __shfl_xor(s, o); ss += __shfl_xor(ss, o); }
  if (!lane) { rb[wave] = s; rb[4 + wave] = ss; }
  __syncthreads();
  float S = rb[0] + rb[1] + rb[2] + rb[3];
  float SS = rb[4] + rb[5] + rb[6] + rb[7];
  float mu = S / (float)D;
  float var = SS / (float)D - mu * mu;
  float rstd = rsqrtf(var + 1e-6f);
  cnt = 0;
  for (int t = tid; t < D; t += 256) {
    float o = (v[cnt++] - mu) * rstd * g[t] + b[t];
    if (dstf) dstf[(size_t)i * D + t] = o;
    if (dstb) dstb[(size_t)i * ostride + ooff + t] = f2b(o);
  }
}

// ---------------- bf16 MFMA GEMM: C[M][N] = A[M][K] * B[N][K]^T ----------------
// 128x128 tile, 256 threads (4 waves, 2x2), each wave 64x64 via 4x4 frags of 16x16x32.
__global__ __launch_bounds__(256) void k_gemm(const unsigned short* __restrict__ A,
                                              const unsigned short* __restrict__ B,
                                              float* __restrict__ C, int K, int N) {
  __shared__ __attribute__((aligned(16))) unsigned short As[128][40];
  __shared__ __attribute__((aligned(16))) unsigned short Bs[128][40];
  int tid = threadIdx.x;
  int row0 = blockIdx.y * 128, col0 = blockIdx.x * 128;
  int wave = tid >> 6, lane = tid & 63;
  int wr = (wave >> 1) * 64, wc = (wave & 1) * 64;
  int sr = tid >> 2, sc = (tid & 3) * 8;
  int lr = lane & 15, lk = (lane >> 4) * 8;
  f32x4 acc[4][4];
#pragma unroll
  for (int m = 0; m < 4; m++)
#pragma unroll
    for (int n = 0; n < 4; n++) acc[m][n] = (f32x4){0.f, 0.f, 0.f, 0.f};

  for (int k0 = 0; k0 < K; k0 += 32) {
    __syncthreads();
#pragma unroll
    for (int p = 0; p < 2; p++) {
      int r = sr + p * 64;
      *reinterpret_cast<uint4*>(&As[r][sc]) =
          *reinterpret_cast<const uint4*>(&A[(size_t)(row0 + r) * K + k0 + sc]);
      *reinterpret_cast<uint4*>(&Bs[r][sc]) =
          *reinterpret_cast<const uint4*>(&B[(size_t)(col0 + r) * K + k0 + sc]);
    }
    __syncthreads();
    bf16x8 af[4], bfr[4];
#pragma unroll
    for (int m = 0; m < 4; m++)
      af[m] = *reinterpret_cast<const bf16x8*>(&As[wr + m * 16 + lr][lk]);
#pragma unroll
    for (int n = 0; n < 4; n++)
      bfr[n] = *reinterpret_cast<const bf16x8*>(&Bs[wc + n * 16 + lr][lk]);
#pragma unroll
    for (int m = 0; m < 4; m++)
#pragma unroll
      for (int n = 0; n < 4; n++)
        acc[m][n] = __builtin_amdgcn_mfma_f32_16x16x32_bf16(af[m], bfr[n], acc[m][n], 0, 0, 0);
  }
  int lq = lane >> 4;
#pragma unroll
  for (int m = 0; m < 4; m++)
#pragma unroll
    for (int n = 0; n < 4; n++)
#pragma unroll
      for (int j = 0; j < 4; j++) {
        int r = row0 + wr + m * 16 + lq * 4 + j;
        int c = col0 + wc + n * 16 + lr;
        C[(size_t)r * N + c] = acc[m][n][j];
      }
}

// ---------------- video banded attention: logits+softmax, write dense att rows ----------------
__global__ __launch_bounds__(256) void k_band_v(const float* __restrict__ Q,
                                                const float* __restrict__ Kp, int stride,
                                                float* __restrict__ att) {
  int i = blockIdx.x, tid = threadIdx.x, wave = tid >> 6, lane = tid & 63;
  __shared__ float qrow[M_DIM];
  __shared__ float logits[40];
  for (int t = tid; t < M_DIM; t += 256) qrow[t] = Q[(size_t)i * stride + t];
  __syncthreads();
  int jlo = max(i - 19, 0), jhi = min(i + 19, N_SEQ - 1), nj = jhi - jlo + 1;
  for (int jj = wave; jj < nj; jj += 4) {
    const float* kr = Kp + (size_t)(jlo + jj) * stride;
    float s = 0.f;
    for (int t = lane; t < M_DIM; t += 64) s += qrow[t] * kr[t];
    for (int o = 32; o; o >>= 1) s += __shfl_xor(s, o);
    if (!lane) logits[jj] = s * 0.06f;
  }
  __syncthreads();
  if (wave == 0) {
    float v = lane < nj ? logits[lane] : -1e30f;
    float mx = v;
    for (int o = 32; o; o >>= 1) mx = fmaxf(mx, __shfl_xor(mx, o));
    float e = lane < nj ? __expf(v - mx) : 0.f;
    float su = e;
    for (int o = 32; o; o >>= 1) su += __shfl_xor(su, o);
    if (lane < nj) att[(size_t)i * N_SEQ + jlo + lane] = e / su;
  }
}

// ---------------- audio banded attention (apperture 40), compact att [N][79] ----------------
__global__ __launch_bounds__(256) void k_band_a(const float* __restrict__ Q,
                                                const float* __restrict__ Kp, int stride,
                                                float* __restrict__ attc) {
  int i = blockIdx.x, tid = threadIdx.x, wave = tid >> 6, lane = tid & 63;
  __shared__ float logits[80];
  int jlo = max(i - 39, 0), jhi = min(i + 39, N_SEQ - 1), nj = jhi - jlo + 1;
  float q0 = Q[(size_t)i * stride + lane];
  float q1 = Q[(size_t)i * stride + 64 + lane];
  for (int jj = wave; jj < nj; jj += 4) {
    const float* kr = Kp + (size_t)(jlo + jj) * stride;
    float s = q0 * kr[lane] + q1 * kr[64 + lane];
    for (int o = 32; o; o >>= 1) s += __shfl_xor(s, o);
    if (!lane) logits[jj] = s * 0.06f;
  }
  __syncthreads();
  if (wave == 0) {
    float v0 = lane < nj ? logits[lane] : -1e30f;
    float v1 = (lane + 64) < nj ? logits[lane + 64] : -1e30f;
    float mx = fmaxf(v0, v1);
    for (int o = 32; o; o >>= 1) mx = fmaxf(mx, __shfl_xor(mx, o));
    float e0 = lane < nj ? __expf(v0 - mx) : 0.f;
    float e1 = (lane + 64) < nj ? __expf(v1 - mx) : 0.f;
    float su = e0 + e1;
    for (int o = 32; o; o >>= 1) su += __shfl_xor(su, o);
    float inv = 1.f / su;
    if (lane < nj) attc[(size_t)i * 79 + lane] = e0 * inv;
    if ((lane + 64) < nj) attc[(size_t)i * 79 + lane + 64] = e1 * inv;
  }
}

// ---------------- y0[i] = sum_j att[j][i] * V[j]  (video, band) -> bf16 ----------------
__global__ __launch_bounds__(256) void k_y0_v(const float* __restrict__ att,
                                              const float* __restrict__ V, int vstride,
                                              unsigned short* __restrict__ y0b) {
  int i = blockIdx.x, tid = threadIdx.x;
  int jlo = max(i - 19, 0), jhi = min(i + 19, N_SEQ - 1);
  float acc[4] = {0.f, 0.f, 0.f, 0.f};
  for (int j = jlo; j <= jhi; j++) {
    float a = att[(size_t)j * N_SEQ + i];
    const float* vr = V + (size_t)j * vstride;
#pragma unroll
    for (int q = 0; q < 4; q++) acc[q] += a * vr[tid + q * 256];
  }
#pragma unroll
  for (int q = 0; q < 4; q++) y0b[(size_t)i * 1024 + tid + q * 256] = f2b(acc[q]);
}

// ---------------- audio y0 (compact att) -> bf16 ----------------
__global__ __launch_bounds__(128) void k_y0_a(const float* __restrict__ attc,
                                              const float* __restrict__ V, int vstride,
                                              unsigned short* __restrict__ y0b) {
  int i = blockIdx.x, tid = threadIdx.x;  // 128 threads
  int jlo = max(i - 39, 0), jhi = min(i + 39, N_SEQ - 1);
  float acc = 0.f;
  for (int j = jlo; j <= jhi; j++) {
    int t = i - max(j - 39, 0);
    float a = attc[(size_t)j * 79 + t];
    acc += a * V[(size_t)j * vstride + tid];
  }
  y0b[(size_t)i * 128 + tid] = f2b(acc);
}

// ---------------- head: relu(h2+b) -> LN -> dot(kd_w) -> sigmoid ----------------
__global__ __launch_bounds__(256) void k_head(const float* __restrict__ h2,
                                              const float* __restrict__ kab,
                                              const float* __restrict__ g,
                                              const float* __restrict__ b,
                                              const float* __restrict__ kdw,
                                              const float* __restrict__ kdb,
                                              float* __restrict__ out) {
  int i = blockIdx.x, tid = threadIdx.x, wave = tid >> 6, lane = tid & 63;
  __shared__ float rb[12];
  float v[4], s = 0.f, ss = 0.f;
#pragma unroll
  for (int q = 0; q < 4; q++) {
    int t = tid + q * 256;
    float x = h2[(size_t)i * 1024 + t] + kab[t];
    x = fmaxf(x, 0.f);
    v[q] = x; s += x; ss += x * x;
  }
  for (int o = 32; o; o >>= 1) { s += __shfl_xor(s, o); ss += __shfl_xor(ss, o); }
  if (!lane) { rb[wave] = s; rb[4 + wave] = ss; }
  __syncthreads();
  float S = rb[0] + rb[1] + rb[2] + rb[3];
  float SS = rb[4] + rb[5] + rb[6] + rb[7];
  float mu = S * (1.f / 1024.f);
  float var = SS * (1.f / 1024.f) - mu * mu;
  float rstd = rsqrtf(var + 1e-6f);
  float d = 0.f;
#pragma unroll
  for (int q = 0; q < 4; q++) {
    int t = tid + q * 256;
    d += ((v[q] - mu) * rstd * g[t] + b[t]) * kdw[t];
  }
  for (int o = 32; o; o >>= 1) d += __shfl_xor(d, o);
  if (!lane) rb[8 + wave] = d;
  __syncthreads();
  if (tid == 0) out[i] = 1.f / (1.f + __expf(-(rb[8] + rb[9] + rb[10] + rb[11] + kdb[0])));
}

extern "C" void kernel_launch(void* const* d_in, const int* in_sizes, int n_in,
                              void* d_out, int out_size, void* d_ws, size_t ws_size,
                              hipStream_t stream) {
  const float* x      = (const float*)d_in[0];
  const float* audio  = (const float*)d_in[1];
  const float* Wk     = (const float*)d_in[2];
  const float* Wq     = (const float*)d_in[3];
  const float* Wv     = (const float*)d_in[4];
  const float* Wo     = (const float*)d_in[5];
  const float* aWk    = (const float*)d_in[6];
  const float* aWq    = (const float*)d_in[7];
  const float* aWv    = (const float*)d_in[8];
  const float* aWo    = (const float*)d_in[9];
  const float* ka_w   = (const float*)d_in[10];
  const float* ka_b   = (const float*)d_in[11];
  const float* kd_w   = (const float*)d_in[12];
  const float* kd_b   = (const float*)d_in[13];
  const float* ln_y_g = (const float*)d_in[14];
  const float* ln_y_b = (const float*)d_in[15];
  const float* ln_ka_g= (const float*)d_in[16];
  const float* ln_ka_b= (const float*)d_in[17];
  const float* ln_a_g = (const float*)d_in[18];
  const float* ln_a_b = (const float*)d_in[19];
  const float* ln_a2_g= (const float*)d_in[20];
  const float* ln_a2_b= (const float*)d_in[21];

  const size_t MB = 1024ull * 1024ull;
  if (ws_size < 132 * MB) return;  // insufficient scratch -> fail loudly (validation will catch)

  char* w = (char*)d_ws;
  float* KQV   = (float*)(w);             // [4096][3072] f32 (K|Q|V)   48MB
  float* y1    = (float*)(w + 48 * MB);   // [4096][1024] f32           16MB
  float* h2    = (float*)(w + 64 * MB);   // [4096][1024] f32           16MB
  float* aKQV  = (float*)(w + 80 * MB);   // [4096][384]  f32            6MB
  float* aud32 = (float*)(w + 86 * MB);   // [4096][128]  f32            2MB
  float* ay1   = (float*)(w + 88 * MB);   // [4096][128]  f32            2MB
  float* attc  = (float*)(w + 90 * MB);   // [4096][79]   f32          1.3MB
  unsigned short* x_bf     = (unsigned short*)(w + 92 * MB);   // 8MB
  unsigned short* wkqv_bf  = (unsigned short*)(w + 100 * MB);  // 6MB
  unsigned short* wo_bf    = (unsigned short*)(w + 106 * MB);  // 2MB
  unsigned short* kaw_bf   = (unsigned short*)(w + 108 * MB);  // 2.25MB
  unsigned short* awkqv_bf = (unsigned short*)(w + 111 * MB);  // 96KB
  unsigned short* awo_bf   = (unsigned short*)(w + 112 * MB);  // 32KB
  unsigned short* aud_bf   = (unsigned short*)(w + 113 * MB);  // 1MB
  unsigned short* y0_bf    = (unsigned short*)(w + 114 * MB);  // 8MB
  unsigned short* ay0_bf   = (unsigned short*)(w + 122 * MB);  // 1MB
  unsigned short* h_bf     = (unsigned short*)(w + 123 * MB);  // 9MB

  float* out0 = (float*)d_out;
  float* att  = (float*)d_out + N_SEQ;

  // zero full output (att zeros outside band + out slot)
  hipMemsetAsync(d_out, 0, (size_t)out_size * sizeof(float), stream);

  auto cvt = [&](const float* s, unsigned short* d, int n) {
    k_f2b<<<dim3((n / 4 + 255) / 256), 256, 0, stream>>>(s, d, n);
  };
  cvt(x, x_bf, N_SEQ * M_DIM);
  cvt(Wk, wkqv_bf, M_DIM * M_DIM);
  cvt(Wq, wkqv_bf + M_DIM * M_DIM, M_DIM * M_DIM);
  cvt(Wv, wkqv_bf + 2 * M_DIM * M_DIM, M_DIM * M_DIM);
  cvt(Wo, wo_bf, M_DIM * M_DIM);
  cvt(ka_w, kaw_bf, 1024 * H_DIM);
  cvt(aWk, awkqv_bf, A_DIM * A_DIM);
  cvt(aWq, awkqv_bf + A_DIM * A_DIM, A_DIM * A_DIM);
  cvt(aWv, awkqv_bf + 2 * A_DIM * A_DIM, A_DIM * A_DIM);
  cvt(aWo, awo_bf, A_DIM * A_DIM);

  // audio LN -> f32 + bf16
  k_ln<<<N_SEQ, 256, 0, stream>>>(audio, nullptr, ln_a2_g, ln_a2_b, aud32, aud_bf,
                                  A_DIM, A_DIM, 0);

  // fused KQV GEMMs
  k_gemm<<<dim3(3072 / 128, N_SEQ / 128), 256, 0, stream>>>(x_bf, wkqv_bf, KQV, 1024, 3072);
  k_gemm<<<dim3(384 / 128, N_SEQ / 128), 256, 0, stream>>>(aud_bf, awkqv_bf, aKQV, 128, 384);

  // banded attention
  k_band_v<<<N_SEQ, 256, 0, stream>>>(KQV + 1024, KQV, 3072, att);
  k_band_a<<<N_SEQ, 256, 0, stream>>>(aKQV + 128, aKQV, 384, attc);

  // y0 = att^T @ V
  k_y0_v<<<N_SEQ, 256, 0, stream>>>(att, KQV + 2048, 3072, y0_bf);
  k_y0_a<<<N_SEQ, 128, 0, stream>>>(attc, aKQV + 256, 384, ay0_bf);

  // output projections
  k_gemm<<<dim3(1024 / 128, N_SEQ / 128), 256, 0, stream>>>(y0_bf, wo_bf, y1, 1024, 1024);
  k_gemm<<<dim3(128 / 128, N_SEQ / 128), 256, 0, stream>>>(ay0_bf, awo_bf, ay1, 128, 128);

  // residual + LN -> h_bf (concat layout [4096][1152])
  k_ln<<<N_SEQ, 256, 0, stream>>>(y1, x, ln_y_g, ln_y_b, nullptr, h_bf, 1024, H_DIM, 0);
  k_ln<<<N_SEQ, 256, 0, stream>>>(ay1, aud32, ln_a_g, ln_a_b, nullptr, h_bf, 128, H_DIM, 1024);

  // MLP GEMM (K=1152)
  k_gemm<<<dim3(1024 / 128, N_SEQ / 128), 256, 0, stream>>>(h_bf, kaw_bf, h2, H_DIM, 1024);

  // relu+bias -> LN -> dot -> sigmoid
  k_head<<<N_SEQ, 256, 0, stream>>>(h2, ka_b, ln_ka_g, ln_ka_b, kd_w, kd_b, out0);
}

// Round 3
// 328.960 us; speedup vs baseline: 1.3527x; 1.3527x over previous
//
#include <hip/hip_runtime.h>
#include <hip/hip_bf16.h>
#include <math.h>

#define N_SEQ 4096
#define M_DIM 1024
#define A_DIM 128
#define H_DIM 1152

typedef __attribute__((ext_vector_type(4))) float f32x4;
typedef __attribute__((ext_vector_type(8))) short bf16x8;
typedef __attribute__((ext_vector_type(4))) short bf16x4;

__device__ __forceinline__ unsigned short f2b(float f) {
  union { float f; unsigned int u; } v; v.f = f;
  unsigned int u = v.u;
  unsigned int r = (u + 0x7fffu + ((u >> 16) & 1u)) >> 16;
  return (unsigned short)r;
}
__device__ __forceinline__ float b2f(unsigned short u) {
  union { unsigned int i; float f; } v; v.i = ((unsigned int)u) << 16; return v.f;
}
// async global->LDS, 16B per lane; lds dest = wave-uniform base + lane*16
__device__ __forceinline__ void gload_lds16(const void* g, void* l) {
  __builtin_amdgcn_global_load_lds((const __attribute__((address_space(1))) unsigned int*)g,
                                   (__attribute__((address_space(3))) unsigned int*)l,
                                   16, 0, 0);
}

// ---------------- float -> bf16 convert ----------------
__global__ __launch_bounds__(256) void k_f2b(const float* __restrict__ src,
                                             unsigned short* __restrict__ dst, int n) {
  int base = (blockIdx.x * 256 + threadIdx.x) * 4;
  if (base + 3 < n) {
    float4 f = *reinterpret_cast<const float4*>(src + base);
    ushort4 o;
    o.x = f2b(f.x); o.y = f2b(f.y); o.z = f2b(f.z); o.w = f2b(f.w);
    *reinterpret_cast<ushort4*>(dst + base) = o;
  }
}

// ---------------- row LayerNorm (optional residual, f32/bf16 out) ----------------
__global__ __launch_bounds__(256) void k_ln(const float* __restrict__ src,
                                            const float* __restrict__ res,
                                            const float* __restrict__ g,
                                            const float* __restrict__ b,
                                            float* __restrict__ dstf,
                                            unsigned short* __restrict__ dstb,
                                            int D, int ostride, int ooff) {
  int i = blockIdx.x, tid = threadIdx.x, wave = tid >> 6, lane = tid & 63;
  __shared__ float rb[8];
  float v[4];
  int cnt = 0;
  float s = 0.f, ss = 0.f;
  for (int t = tid; t < D; t += 256) {
    float x = src[(size_t)i * D + t];
    if (res) x += res[(size_t)i * D + t];
    v[cnt++] = x; s += x; ss += x * x;
  }
  for (int o = 32; o; o >>= 1) { s += __shfl_xor(s, o); ss += __shfl_xor(ss, o); }
  if (!lane) { rb[wave] = s; rb[4 + wave] = ss; }
  __syncthreads();
  float S = rb[0] + rb[1] + rb[2] + rb[3];
  float SS = rb[4] + rb[5] + rb[6] + rb[7];
  float mu = S / (float)D;
  float var = SS / (float)D - mu * mu;
  float rstd = rsqrtf(var + 1e-6f);
  cnt = 0;
  for (int t = tid; t < D; t += 256) {
    float o = (v[cnt++] - mu) * rstd * g[t] + b[t];
    if (dstf) dstf[(size_t)i * D + t] = o;
    if (dstb) dstb[(size_t)i * ostride + ooff + t] = f2b(o);
  }
}

// ---------------- bf16 MFMA GEMM (m97-style global_load_lds staging) ----------------
// C[M][N] = A[M][K] * B[N][K]^T ; 128x128 tile, 4 waves, 4x4 frags of 16x16x32.
__global__ __launch_bounds__(256) void k_gemm(const unsigned short* __restrict__ A,
                                              const unsigned short* __restrict__ B,
                                              float* __restrict__ Cf,
                                              unsigned short* __restrict__ Cb,
                                              int K, int N) {
  __shared__ __attribute__((aligned(16))) unsigned short As[128 * 32];
  __shared__ __attribute__((aligned(16))) unsigned short Bs[128 * 32];
  int tid = threadIdx.x;
  int row0 = blockIdx.y * 128, col0 = blockIdx.x * 128;
  int wave = tid >> 6, lane = tid & 63;
  int wr = (wave >> 1) * 64, wc = (wave & 1) * 64;
  int lr = lane & 15;
  int lkb = (lane >> 4) * 16;          // byte offset of 8-elem k-group
  int ch = wave * 2;                   // this wave stages chunks ch, ch+1 (16 rows each)
  int srow = ch * 16 + (lane >> 2);    // global row staged by this lane
  int scol = (lane & 3) * 8;           // elem col staged by this lane
  const unsigned short* ga0 = A + (size_t)(row0 + srow) * K + scol;
  const unsigned short* ga1 = ga0 + (size_t)16 * K;
  const unsigned short* gb0 = B + (size_t)(col0 + srow) * K + scol;
  const unsigned short* gb1 = gb0 + (size_t)16 * K;
  char* la0 = (char*)As + ch * 1024;
  char* la1 = la0 + 1024;
  char* lb0 = (char*)Bs + ch * 1024;
  char* lb1 = lb0 + 1024;
  const char* pa = (const char*)As + (wr + lr) * 64 + lkb;
  const char* pb = (const char*)Bs + (wc + lr) * 64 + lkb;

  f32x4 acc[4][4];
#pragma unroll
  for (int m = 0; m < 4; m++)
#pragma unroll
    for (int n = 0; n < 4; n++) acc[m][n] = (f32x4){0.f, 0.f, 0.f, 0.f};

  for (int k0 = 0; k0 < K; k0 += 32) {
    __syncthreads();
    gload_lds16(ga0 + k0, la0);
    gload_lds16(ga1 + k0, la1);
    gload_lds16(gb0 + k0, lb0);
    gload_lds16(gb1 + k0, lb1);
    __syncthreads();
    bf16x8 af[4], bfr[4];
#pragma unroll
    for (int m = 0; m < 4; m++) af[m] = *(const bf16x8*)(pa + m * 1024);
#pragma unroll
    for (int n = 0; n < 4; n++) bfr[n] = *(const bf16x8*)(pb + n * 1024);
#pragma unroll
    for (int m = 0; m < 4; m++)
#pragma unroll
      for (int n = 0; n < 4; n++)
        acc[m][n] = __builtin_amdgcn_mfma_f32_16x16x32_bf16(af[m], bfr[n], acc[m][n], 0, 0, 0);
  }
  int lq = lane >> 4;
#pragma unroll
  for (int m = 0; m < 4; m++)
#pragma unroll
    for (int n = 0; n < 4; n++)
#pragma unroll
      for (int j = 0; j < 4; j++) {
        int r = row0 + wr + m * 16 + lq * 4 + j;
        int c = col0 + wc + n * 16 + lr;
        if (Cf) Cf[(size_t)r * N + c] = acc[m][n][j];
        if (Cb) Cb[(size_t)r * N + c] = f2b(acc[m][n][j]);
      }
}

// ---------------- video banded attention: 16 Q-rows/block, MFMA QK^T ----------------
// kqv: bf16 [4096][3072] = K|Q|V. Outputs: dense att rows (band only) + compact P[4096][40].
__global__ __launch_bounds__(256) void k_attn_v(const unsigned short* __restrict__ kqv,
                                                float* __restrict__ att,
                                                float* __restrict__ P) {
  __shared__ unsigned short Qs[16][264];
  __shared__ unsigned short Ks[64][264];
  __shared__ float lg[16][64];
  int tid = threadIdx.x, wave = tid >> 6, lane = tid & 63;
  int i0 = blockIdx.x * 16;
  int jlo = max(i0 - 19, 0);
  int jhi = min(i0 + 34, N_SEQ - 1);
  int nk = jhi - jlo + 1;                  // <= 54
  int lr = lane & 15, lke = (lane >> 4) * 8;
  f32x4 acc = (f32x4){0.f, 0.f, 0.f, 0.f};
  for (int kc = 0; kc < M_DIM; kc += 256) {
    __syncthreads();
#pragma unroll
    for (int it = 0; it < 2; it++) {
      int q = tid + it * 256;              // < 512
      int r = q >> 5, c = (q & 31) * 8;
      *(bf16x8*)&Qs[r][c] =
          *(const bf16x8*)&kqv[(size_t)(i0 + r) * 3072 + 1024 + kc + c];
    }
#pragma unroll
    for (int it = 0; it < 8; it++) {
      int q = tid + it * 256;              // < 2048
      int r = q >> 5, c = (q & 31) * 8;
      bf16x8 v = {0, 0, 0, 0, 0, 0, 0, 0};
      if (r < nk) v = *(const bf16x8*)&kqv[(size_t)(jlo + r) * 3072 + kc + c];
      *(bf16x8*)&Ks[r][c] = v;
    }
    __syncthreads();
#pragma unroll
    for (int kk = 0; kk < 8; kk++) {
      bf16x8 a = *(const bf16x8*)&Qs[lr][kk * 32 + lke];
      bf16x8 b = *(const bf16x8*)&Ks[wave * 16 + lr][kk * 32 + lke];
      acc = __builtin_amdgcn_mfma_f32_16x16x32_bf16(a, b, acc, 0, 0, 0);
    }
  }
#pragma unroll
  for (int j = 0; j < 4; j++)
    lg[(lane >> 4) * 4 + j][wave * 16 + (lane & 15)] = acc[j] * 0.06f;
  __syncthreads();
#pragma unroll
  for (int q = 0; q < 4; q++) {
    int r = wave + q * 4;
    int i = i0 + r;
    int c = lane;                           // < 64
    int d = i - (jlo + c);
    bool valid = (c < nk) && (d > -20) && (d < 20);
    float v = valid ? lg[r][c] : -1e30f;
    float mx = v;
    for (int o = 32; o; o >>= 1) mx = fmaxf(mx, __shfl_xor(mx, o));
    float e = valid ? __expf(v - mx) : 0.f;
    float su = e;
    for (int o = 32; o; o >>= 1) su += __shfl_xor(su, o);
    float p = e / su;
    if (valid) {
      att[(size_t)i * N_SEQ + jlo + c] = p;
      P[(size_t)i * 40 + (jlo + c) - max(i - 19, 0)] = p;
    }
  }
}

// ---------------- video PV: y0[i] = sum_j att[j][i] * V[j]  (TRANSPOSED att!) ----------------
// att[j][i] lives at compact P[j*40 + i - max(j-19,0)].
__global__ __launch_bounds__(256) void k_pv_v(const float* __restrict__ P,
                                              const unsigned short* __restrict__ kqv,
                                              unsigned short* __restrict__ y0b) {
  __shared__ unsigned short Vs[54][1024];
  __shared__ float Ps[54 * 40];
  int tid = threadIdx.x;
  int i0 = blockIdx.x * 16;
  int jlo_b = max(i0 - 19, 0);
  int jhi_b = min(i0 + 34, N_SEQ - 1);
  int nv = jhi_b - jlo_b + 1;               // <= 54
#pragma unroll
  for (int it = 0; it < 27; it++) {
    int q = tid + it * 256;                 // < 6912
    int r = q >> 7, c = (q & 127) * 8;
    if (r < nv)
      *(bf16x8*)&Vs[r][c] =
          *(const bf16x8*)&kqv[(size_t)(jlo_b + r) * 3072 + 2048 + c];
  }
  for (int q = tid; q < nv * 40; q += 256)
    Ps[q] = P[(size_t)jlo_b * 40 + q];
  __syncthreads();
  int d0 = tid * 4;
  for (int rr = 0; rr < 16; rr++) {
    int i = i0 + rr;
    int jlo_i = max(i - 19, 0);
    int jhi_i = min(i + 19, N_SEQ - 1);
    float a0 = 0.f, a1 = 0.f, a2 = 0.f, a3 = 0.f;
    for (int j = jlo_i; j <= jhi_i; j++) {
      float a = Ps[(j - jlo_b) * 40 + (i - max(j - 19, 0))];   // att[j][i]
      bf16x4 v = *(const bf16x4*)&Vs[j - jlo_b][d0];
      a0 += a * b2f((unsigned short)v[0]);
      a1 += a * b2f((unsigned short)v[1]);
      a2 += a * b2f((unsigned short)v[2]);
      a3 += a * b2f((unsigned short)v[3]);
    }
    ushort4 o;
    o.x = f2b(a0); o.y = f2b(a1); o.z = f2b(a2); o.w = f2b(a3);
    *(ushort4*)&y0b[(size_t)i * 1024 + d0] = o;
  }
}

// ---------------- audio banded attention: 32 rows/block, MFMA, compact Pa[4096][79] ----------------
__global__ __launch_bounds__(256) void k_attn_a(const unsigned short* __restrict__ akqv,
                                                float* __restrict__ Pa) {
  __shared__ unsigned short Qs[32][136];
  __shared__ unsigned short Ks[112][136];
  __shared__ float lg[32][112];
  int tid = threadIdx.x, wave = tid >> 6, lane = tid & 63;
  int i0 = blockIdx.x * 32;
  int jlo = max(i0 - 39, 0);
  int jhi = min(i0 + 70, N_SEQ - 1);
  int nk = jhi - jlo + 1;                   // <= 110
  int lr = lane & 15, lke = (lane >> 4) * 8;
#pragma unroll
  for (int it = 0; it < 2; it++) {
    int q = tid + it * 256;                 // < 512
    int r = q >> 4, c = (q & 15) * 8;
    *(bf16x8*)&Qs[r][c] = *(const bf16x8*)&akqv[(size_t)(i0 + r) * 384 + 128 + c];
  }
#pragma unroll
  for (int it = 0; it < 7; it++) {
    int q = tid + it * 256;                 // < 1792
    int r = q >> 4, c = (q & 15) * 8;
    bf16x8 v = {0, 0, 0, 0, 0, 0, 0, 0};
    if (r < nk) v = *(const bf16x8*)&akqv[(size_t)(jlo + r) * 384 + c];
    *(bf16x8*)&Ks[r][c] = v;
  }
  __syncthreads();
  for (int ff = wave; ff < 14; ff += 4) {
    int fr = ff / 7, fc = ff % 7;
    f32x4 acc = (f32x4){0.f, 0.f, 0.f, 0.f};
#pragma unroll
    for (int kk = 0; kk < 4; kk++) {
      bf16x8 a = *(const bf16x8*)&Qs[fr * 16 + lr][kk * 32 + lke];
      bf16x8 b = *(const bf16x8*)&Ks[fc * 16 + lr][kk * 32 + lke];
      acc = __builtin_amdgcn_mfma_f32_16x16x32_bf16(a, b, acc, 0, 0, 0);
    }
#pragma unroll
    for (int j = 0; j < 4; j++)
      lg[fr * 16 + (lane >> 4) * 4 + j][fc * 16 + (lane & 15)] = acc[j] * 0.06f;
  }
  __syncthreads();
#pragma unroll
  for (int q = 0; q < 8; q++) {
    int r = wave + q * 4;                   // 0..31
    int i = i0 + r;
    int c0 = lane, c1 = lane + 64;
    int e0i = i - (jlo + c0), e1i = i - (jlo + c1);
    bool v0 = (c0 < nk) && (e0i > -40) && (e0i < 40);
    bool v1 = (c1 < nk) && (e1i > -40) && (e1i < 40);
    float l0 = v0 ? lg[r][c0] : -1e30f;
    float l1 = v1 ? lg[r][min(c1, 111)] : -1e30f;
    float mx = fmaxf(l0, l1);
    for (int o = 32; o; o >>= 1) mx = fmaxf(mx, __shfl_xor(mx, o));
    float e0 = v0 ? __expf(l0 - mx) : 0.f;
    float e1 = v1 ? __expf(l1 - mx) : 0.f;
    float su = e0 + e1;
    for (int o = 32; o; o >>= 1) su += __shfl_xor(su, o);
    float inv = 1.f / su;
    int base = max(i - 39, 0);
    if (v0) Pa[(size_t)i * 79 + (jlo + c0) - base] = e0 * inv;
    if (v1) Pa[(size_t)i * 79 + (jlo + c1) - base] = e1 * inv;
  }
}

// ---------------- audio PV: y0[i] = sum_j att[j][i] * V[j]  (TRANSPOSED att!) ----------------
__global__ __launch_bounds__(256) void k_pv_a(const float* __restrict__ Pa,
                                              const unsigned short* __restrict__ akqv,
                                              unsigned short* __restrict__ y0b) {
  __shared__ unsigned short Vs[110][128];
  __shared__ float Pas[110 * 79];
  int tid = threadIdx.x;
  int i0 = blockIdx.x * 32;
  int jlo_b = max(i0 - 39, 0);
  int jhi_b = min(i0 + 70, N_SEQ - 1);
  int nv = jhi_b - jlo_b + 1;               // <= 110
#pragma unroll
  for (int it = 0; it < 7; it++) {
    int q = tid + it * 256;                 // < 1792
    int r = q >> 4, c = (q & 15) * 8;
    if (r < nv)
      *(bf16x8*)&Vs[r][c] = *(const bf16x8*)&akqv[(size_t)(jlo_b + r) * 384 + 256 + c];
  }
  for (int q = tid; q < nv * 79; q += 256)
    Pas[q] = Pa[(size_t)jlo_b * 79 + q];
  __syncthreads();
  int u = tid >> 7, d = tid & 127;
  for (int rr = u; rr < 32; rr += 2) {
    int i = i0 + rr;
    int jlo_i = max(i - 39, 0);
    int jhi_i = min(i + 39, N_SEQ - 1);
    float acc = 0.f;
    for (int j = jlo_i; j <= jhi_i; j++)
      acc += Pas[(j - jlo_b) * 79 + (i - max(j - 39, 0))] * b2f(Vs[j - jlo_b][d]);
    y0b[(size_t)i * 128 + d] = f2b(acc);
  }
}

// ---------------- head: relu(h2+b) -> LN -> dot(kd_w) -> sigmoid ----------------
__global__ __launch_bounds__(256) void k_head(const float* __restrict__ h2,
                                              const float* __restrict__ kab,
                                              const float* __restrict__ g,
                                              const float* __restrict__ b,
                                              const float* __restrict__ kdw,
                                              const float* __restrict__ kdb,
                                              float* __restrict__ out) {
  int i = blockIdx.x, tid = threadIdx.x, wave = tid >> 6, lane = tid & 63;
  __shared__ float rb[12];
  float v[4], s = 0.f, ss = 0.f;
#pragma unroll
  for (int q = 0; q < 4; q++) {
    int t = tid + q * 256;
    float x = h2[(size_t)i * 1024 + t] + kab[t];
    x = fmaxf(x, 0.f);
    v[q] = x; s += x; ss += x * x;
  }
  for (int o = 32; o; o >>= 1) { s += __shfl_xor(s, o); ss += __shfl_xor(ss, o); }
  if (!lane) { rb[wave] = s; rb[4 + wave] = ss; }
  __syncthreads();
  float S = rb[0] + rb[1] + rb[2] + rb[3];
  float SS = rb[4] + rb[5] + rb[6] + rb[7];
  float mu = S * (1.f / 1024.f);
  float var = SS * (1.f / 1024.f) - mu * mu;
  float rstd = rsqrtf(var + 1e-6f);
  float dacc = 0.f;
#pragma unroll
  for (int q = 0; q < 4; q++) {
    int t = tid + q * 256;
    dacc += ((v[q] - mu) * rstd * g[t] + b[t]) * kdw[t];
  }
  for (int o = 32; o; o >>= 1) dacc += __shfl_xor(dacc, o);
  if (!lane) rb[8 + wave] = dacc;
  __syncthreads();
  if (tid == 0) out[i] = 1.f / (1.f + __expf(-(rb[8] + rb[9] + rb[10] + rb[11] + kdb[0])));
}

extern "C" void kernel_launch(void* const* d_in, const int* in_sizes, int n_in,
                              void* d_out, int out_size, void* d_ws, size_t ws_size,
                              hipStream_t stream) {
  const float* x      = (const float*)d_in[0];
  const float* audio  = (const float*)d_in[1];
  const float* Wk     = (const float*)d_in[2];
  const float* Wq     = (const float*)d_in[3];
  const float* Wv     = (const float*)d_in[4];
  const float* Wo     = (const float*)d_in[5];
  const float* aWk    = (const float*)d_in[6];
  const float* aWq    = (const float*)d_in[7];
  const float* aWv    = (const float*)d_in[8];
  const float* aWo    = (const float*)d_in[9];
  const float* ka_w   = (const float*)d_in[10];
  const float* ka_b   = (const float*)d_in[11];
  const float* kd_w   = (const float*)d_in[12];
  const float* kd_b   = (const float*)d_in[13];
  const float* ln_y_g = (const float*)d_in[14];
  const float* ln_y_b = (const float*)d_in[15];
  const float* ln_ka_g= (const float*)d_in[16];
  const float* ln_ka_b= (const float*)d_in[17];
  const float* ln_a_g = (const float*)d_in[18];
  const float* ln_a_b = (const float*)d_in[19];
  const float* ln_a2_g= (const float*)d_in[20];
  const float* ln_a2_b= (const float*)d_in[21];

  const size_t MB = 1024ull * 1024ull;
  if (ws_size < 106 * MB) return;

  char* w = (char*)d_ws;
  unsigned short* kqv_bf  = (unsigned short*)(w);            // [4096][3072] bf16  24MB
  unsigned short* akqv_bf = (unsigned short*)(w + 24 * MB);  // [4096][384]  bf16   3MB
  float* y1    = (float*)(w + 27 * MB);                      // [4096][1024]       16MB
  float* h2    = (float*)(w + 43 * MB);                      // [4096][1024]       16MB
  float* aud32 = (float*)(w + 59 * MB);                      // [4096][128]         2MB
  float* ay1   = (float*)(w + 61 * MB);                      // [4096][128]         2MB
  float* P     = (float*)(w + 63 * MB);                      // [4096][40]        640KB
  float* Pa    = (float*)(w + 64 * MB);                      // [4096][79]        1.3MB
  unsigned short* x_bf     = (unsigned short*)(w + 66 * MB); // 8MB
  unsigned short* wkqv_bf  = (unsigned short*)(w + 74 * MB); // 6MB
  unsigned short* wo_bf    = (unsigned short*)(w + 80 * MB); // 2MB
  unsigned short* kaw_bf   = (unsigned short*)(w + 82 * MB); // 2.25MB
  unsigned short* awkqv_bf = (unsigned short*)(w + 85 * MB); // 96KB
  unsigned short* awo_bf   = (unsigned short*)(w + 86 * MB); // 32KB
  unsigned short* aud_bf   = (unsigned short*)(w + 87 * MB); // 1MB
  unsigned short* y0_bf    = (unsigned short*)(w + 88 * MB); // 8MB
  unsigned short* ay0_bf   = (unsigned short*)(w + 96 * MB); // 1MB
  unsigned short* h_bf     = (unsigned short*)(w + 97 * MB); // 9MB

  float* out0 = (float*)d_out;
  float* att  = (float*)d_out + N_SEQ;

  // zeros outside the band + out slot
  hipMemsetAsync(d_out, 0, (size_t)out_size * sizeof(float), stream);

  auto cvt = [&](const float* s, unsigned short* d, int n) {
    k_f2b<<<dim3((n / 4 + 255) / 256), 256, 0, stream>>>(s, d, n);
  };
  cvt(x, x_bf, N_SEQ * M_DIM);
  cvt(Wk, wkqv_bf, M_DIM * M_DIM);
  cvt(Wq, wkqv_bf + M_DIM * M_DIM, M_DIM * M_DIM);
  cvt(Wv, wkqv_bf + 2 * M_DIM * M_DIM, M_DIM * M_DIM);
  cvt(Wo, wo_bf, M_DIM * M_DIM);
  cvt(ka_w, kaw_bf, 1024 * H_DIM);
  cvt(aWk, awkqv_bf, A_DIM * A_DIM);
  cvt(aWq, awkqv_bf + A_DIM * A_DIM, A_DIM * A_DIM);
  cvt(aWv, awkqv_bf + 2 * A_DIM * A_DIM, A_DIM * A_DIM);
  cvt(aWo, awo_bf, A_DIM * A_DIM);

  // audio LN -> f32 (residual) + bf16 (GEMM input)
  k_ln<<<N_SEQ, 256, 0, stream>>>(audio, nullptr, ln_a2_g, ln_a2_b, aud32, aud_bf,
                                  A_DIM, A_DIM, 0);

  // fused KQV GEMMs -> bf16 only
  k_gemm<<<dim3(24, 32), 256, 0, stream>>>(x_bf, wkqv_bf, nullptr, kqv_bf, 1024, 3072);
  k_gemm<<<dim3(3, 32), 256, 0, stream>>>(aud_bf, awkqv_bf, nullptr, akqv_bf, 128, 384);

  // banded attention (tiled, MFMA) + PV
  k_attn_v<<<256, 256, 0, stream>>>(kqv_bf, att, P);
  k_pv_v<<<256, 256, 0, stream>>>(P, kqv_bf, y0_bf);
  k_attn_a<<<128, 256, 0, stream>>>(akqv_bf, Pa);
  k_pv_a<<<128, 256, 0, stream>>>(Pa, akqv_bf, ay0_bf);

  // output projections
  k_gemm<<<dim3(8, 32), 256, 0, stream>>>(y0_bf, wo_bf, y1, nullptr, 1024, 1024);
  k_gemm<<<dim3(1, 32), 256, 0, stream>>>(ay0_bf, awo_bf, ay1, nullptr, 128, 128);

  // residual + LN -> h_bf (concat layout [4096][1152])
  k_ln<<<N_SEQ, 256, 0, stream>>>(y1, x, ln_y_g, ln_y_b, nullptr, h_bf, 1024, H_DIM, 0);
  k_ln<<<N_SEQ, 256, 0, stream>>>(ay1, aud32, ln_a_g, ln_a_b, nullptr, h_bf, 128, H_DIM, 1024);

  // MLP GEMM (K=1152)
  k_gemm<<<dim3(8, 32), 256, 0, stream>>>(h_bf, kaw_bf, h2, nullptr, H_DIM, 1024);

  // relu+bias -> LN -> dot -> sigmoid
  k_head<<<N_SEQ, 256, 0, stream>>>(h2, ka_b, ln_ka_g, ln_ka_b, kd_w, kd_b, out0);
}

// Round 4
// 268.433 us; speedup vs baseline: 1.6577x; 1.2255x over previous
//
#include <hip/hip_runtime.h>
#include <hip/hip_bf16.h>
#include <math.h>

#define N_SEQ 4096
#define M_DIM 1024
#define A_DIM 128
#define H_DIM 1152

typedef __attribute__((ext_vector_type(4))) float f32x4;
typedef __attribute__((ext_vector_type(8))) short bf16x8;
typedef __attribute__((ext_vector_type(4))) short bf16x4;

__device__ __forceinline__ unsigned short f2b(float f) {
  union { float f; unsigned int u; } v; v.f = f;
  unsigned int u = v.u;
  unsigned int r = (u + 0x7fffu + ((u >> 16) & 1u)) >> 16;
  return (unsigned short)r;
}
__device__ __forceinline__ float b2f(unsigned short u) {
  union { unsigned int i; float f; } v; v.i = ((unsigned int)u) << 16; return v.f;
}
// async global->LDS, 16B per lane; lds dest = wave-uniform base + lane*16
__device__ __forceinline__ void gload_lds16(const void* g, void* l) {
  __builtin_amdgcn_global_load_lds((const __attribute__((address_space(1))) unsigned int*)g,
                                   (__attribute__((address_space(3))) unsigned int*)l,
                                   16, 0, 0);
}

// ---------------- float -> bf16 convert ----------------
__global__ __launch_bounds__(256) void k_f2b(const float* __restrict__ src,
                                             unsigned short* __restrict__ dst, int n) {
  int base = (blockIdx.x * 256 + threadIdx.x) * 4;
  if (base + 3 < n) {
    float4 f = *reinterpret_cast<const float4*>(src + base);
    ushort4 o;
    o.x = f2b(f.x); o.y = f2b(f.y); o.z = f2b(f.z); o.w = f2b(f.w);
    *reinterpret_cast<ushort4*>(dst + base) = o;
  }
}

// ---------------- row LayerNorm (optional residual, f32/bf16 out) ----------------
__global__ __launch_bounds__(256) void k_ln(const float* __restrict__ src,
                                            const float* __restrict__ res,
                                            const float* __restrict__ g,
                                            const float* __restrict__ b,
                                            float* __restrict__ dstf,
                                            unsigned short* __restrict__ dstb,
                                            int D, int ostride, int ooff) {
  int i = blockIdx.x, tid = threadIdx.x, wave = tid >> 6, lane = tid & 63;
  __shared__ float rb[8];
  float v[4];
  int cnt = 0;
  float s = 0.f, ss = 0.f;
  for (int t = tid; t < D; t += 256) {
    float x = src[(size_t)i * D + t];
    if (res) x += res[(size_t)i * D + t];
    v[cnt++] = x; s += x; ss += x * x;
  }
  for (int o = 32; o; o >>= 1) { s += __shfl_xor(s, o); ss += __shfl_xor(ss, o); }
  if (!lane) { rb[wave] = s; rb[4 + wave] = ss; }
  __syncthreads();
  float S = rb[0] + rb[1] + rb[2] + rb[3];
  float SS = rb[4] + rb[5] + rb[6] + rb[7];
  float mu = S / (float)D;
  float var = SS / (float)D - mu * mu;
  float rstd = rsqrtf(var + 1e-6f);
  cnt = 0;
  for (int t = tid; t < D; t += 256) {
    float o = (v[cnt++] - mu) * rstd * g[t] + b[t];
    if (dstf) dstf[(size_t)i * D + t] = o;
    if (dstb) dstb[(size_t)i * ostride + ooff + t] = f2b(o);
  }
}

// ---------------- bf16 MFMA GEMM (m97-style global_load_lds staging) ----------------
// C[M][N] = A[M][K] * B[N][K]^T ; 128x128 tile, 4 waves, 4x4 frags of 16x16x32.
__global__ __launch_bounds__(256) void k_gemm(const unsigned short* __restrict__ A,
                                              const unsigned short* __restrict__ B,
                                              float* __restrict__ Cf,
                                              unsigned short* __restrict__ Cb,
                                              int K, int N) {
  __shared__ __attribute__((aligned(16))) unsigned short As[128 * 32];
  __shared__ __attribute__((aligned(16))) unsigned short Bs[128 * 32];
  int tid = threadIdx.x;
  int row0 = blockIdx.y * 128, col0 = blockIdx.x * 128;
  int wave = tid >> 6, lane = tid & 63;
  int wr = (wave >> 1) * 64, wc = (wave & 1) * 64;
  int lr = lane & 15;
  int lkb = (lane >> 4) * 16;          // byte offset of 8-elem k-group
  int ch = wave * 2;                   // this wave stages chunks ch, ch+1 (16 rows each)
  int srow = ch * 16 + (lane >> 2);    // global row staged by this lane
  int scol = (lane & 3) * 8;           // elem col staged by this lane
  const unsigned short* ga0 = A + (size_t)(row0 + srow) * K + scol;
  const unsigned short* ga1 = ga0 + (size_t)16 * K;
  const unsigned short* gb0 = B + (size_t)(col0 + srow) * K + scol;
  const unsigned short* gb1 = gb0 + (size_t)16 * K;
  char* la0 = (char*)As + ch * 1024;
  char* la1 = la0 + 1024;
  char* lb0 = (char*)Bs + ch * 1024;
  char* lb1 = lb0 + 1024;
  const char* pa = (const char*)As + (wr + lr) * 64 + lkb;
  const char* pb = (const char*)Bs + (wc + lr) * 64 + lkb;

  f32x4 acc[4][4];
#pragma unroll
  for (int m = 0; m < 4; m++)
#pragma unroll
    for (int n = 0; n < 4; n++) acc[m][n] = (f32x4){0.f, 0.f, 0.f, 0.f};

  for (int k0 = 0; k0 < K; k0 += 32) {
    __syncthreads();
    gload_lds16(ga0 + k0, la0);
    gload_lds16(ga1 + k0, la1);
    gload_lds16(gb0 + k0, lb0);
    gload_lds16(gb1 + k0, lb1);
    __syncthreads();
    bf16x8 af[4], bfr[4];
#pragma unroll
    for (int m = 0; m < 4; m++) af[m] = *(const bf16x8*)(pa + m * 1024);
#pragma unroll
    for (int n = 0; n < 4; n++) bfr[n] = *(const bf16x8*)(pb + n * 1024);
#pragma unroll
    for (int m = 0; m < 4; m++)
#pragma unroll
      for (int n = 0; n < 4; n++)
        acc[m][n] = __builtin_amdgcn_mfma_f32_16x16x32_bf16(af[m], bfr[n], acc[m][n], 0, 0, 0);
  }
  int lq = lane >> 4;
#pragma unroll
  for (int m = 0; m < 4; m++)
#pragma unroll
    for (int n = 0; n < 4; n++)
#pragma unroll
      for (int j = 0; j < 4; j++) {
        int r = row0 + wr + m * 16 + lq * 4 + j;
        int c = col0 + wc + n * 16 + lr;
        if (Cf) Cf[(size_t)r * N + c] = acc[m][n][j];
        if (Cb) Cb[(size_t)r * N + c] = f2b(acc[m][n][j]);
      }
}

// ---------------- video banded attention: 16 Q-rows/block, MFMA QK^T ----------------
// kqv: bf16 [4096][3072] = K|Q|V. Outputs: dense att rows (band only) + compact P[4096][40].
__global__ __launch_bounds__(256) void k_attn_v(const unsigned short* __restrict__ kqv,
                                                float* __restrict__ att,
                                                float* __restrict__ P) {
  __shared__ unsigned short Qs[16][264];
  __shared__ unsigned short Ks[64][264];
  __shared__ float lg[16][64];
  int tid = threadIdx.x, wave = tid >> 6, lane = tid & 63;
  int i0 = blockIdx.x * 16;
  int jlo = max(i0 - 19, 0);
  int jhi = min(i0 + 34, N_SEQ - 1);
  int nk = jhi - jlo + 1;                  // <= 54
  int lr = lane & 15, lke = (lane >> 4) * 8;
  f32x4 acc = (f32x4){0.f, 0.f, 0.f, 0.f};
  for (int kc = 0; kc < M_DIM; kc += 256) {
    __syncthreads();
#pragma unroll
    for (int it = 0; it < 2; it++) {
      int q = tid + it * 256;              // < 512
      int r = q >> 5, c = (q & 31) * 8;
      *(bf16x8*)&Qs[r][c] =
          *(const bf16x8*)&kqv[(size_t)(i0 + r) * 3072 + 1024 + kc + c];
    }
#pragma unroll
    for (int it = 0; it < 8; it++) {
      int q = tid + it * 256;              // < 2048
      int r = q >> 5, c = (q & 31) * 8;
      bf16x8 v = {0, 0, 0, 0, 0, 0, 0, 0};
      if (r < nk) v = *(const bf16x8*)&kqv[(size_t)(jlo + r) * 3072 + kc + c];
      *(bf16x8*)&Ks[r][c] = v;
    }
    __syncthreads();
#pragma unroll
    for (int kk = 0; kk < 8; kk++) {
      bf16x8 a = *(const bf16x8*)&Qs[lr][kk * 32 + lke];
      bf16x8 b = *(const bf16x8*)&Ks[wave * 16 + lr][kk * 32 + lke];
      acc = __builtin_amdgcn_mfma_f32_16x16x32_bf16(a, b, acc, 0, 0, 0);
    }
  }
#pragma unroll
  for (int j = 0; j < 4; j++)
    lg[(lane >> 4) * 4 + j][wave * 16 + (lane & 15)] = acc[j] * 0.06f;
  __syncthreads();
#pragma unroll
  for (int q = 0; q < 4; q++) {
    int r = wave + q * 4;
    int i = i0 + r;
    int c = lane;                           // < 64
    int d = i - (jlo + c);
    bool valid = (c < nk) && (d > -20) && (d < 20);
    float v = valid ? lg[r][c] : -1e30f;
    float mx = v;
    for (int o = 32; o; o >>= 1) mx = fmaxf(mx, __shfl_xor(mx, o));
    float e = valid ? __expf(v - mx) : 0.f;
    float su = e;
    for (int o = 32; o; o >>= 1) su += __shfl_xor(su, o);
    float p = e / su;
    if (valid) {
      att[(size_t)i * N_SEQ + jlo + c] = p;
      P[(size_t)i * 40 + (jlo + c) - max(i - 19, 0)] = p;
    }
  }
}

// ---------------- video PV: one block per row i; y0[i][d] = sum_j att[j][i]*V[j][d] ----------------
// att[j][i] at compact P[j*40 + i - max(j-19,0)]. V rows L2-resident (reused ~39x).
__global__ __launch_bounds__(256) void k_pv_v(const float* __restrict__ P,
                                              const unsigned short* __restrict__ kqv,
                                              unsigned short* __restrict__ y0b) {
  int i = blockIdx.x, tid = threadIdx.x;
  int jlo = max(i - 19, 0), jhi = min(i + 19, N_SEQ - 1);
  int d0 = tid * 4;
  float a0 = 0.f, a1 = 0.f, a2 = 0.f, a3 = 0.f;
  for (int j = jlo; j <= jhi; j++) {
    float a = P[(size_t)j * 40 + (i - max(j - 19, 0))];        // att[j][i]
    bf16x4 v = *(const bf16x4*)&kqv[(size_t)j * 3072 + 2048 + d0];
    a0 += a * b2f((unsigned short)v[0]);
    a1 += a * b2f((unsigned short)v[1]);
    a2 += a * b2f((unsigned short)v[2]);
    a3 += a * b2f((unsigned short)v[3]);
  }
  ushort4 o;
  o.x = f2b(a0); o.y = f2b(a1); o.z = f2b(a2); o.w = f2b(a3);
  *(ushort4*)&y0b[(size_t)i * 1024 + d0] = o;
}

// ---------------- audio banded attention: 32 rows/block, MFMA, compact Pa[4096][79] ----------------
__global__ __launch_bounds__(256) void k_attn_a(const unsigned short* __restrict__ akqv,
                                                float* __restrict__ Pa) {
  __shared__ unsigned short Qs[32][136];
  __shared__ unsigned short Ks[112][136];
  __shared__ float lg[32][112];
  int tid = threadIdx.x, wave = tid >> 6, lane = tid & 63;
  int i0 = blockIdx.x * 32;
  int jlo = max(i0 - 39, 0);
  int jhi = min(i0 + 70, N_SEQ - 1);
  int nk = jhi - jlo + 1;                   // <= 110
  int lr = lane & 15, lke = (lane >> 4) * 8;
#pragma unroll
  for (int it = 0; it < 2; it++) {
    int q = tid + it * 256;                 // < 512
    int r = q >> 4, c = (q & 15) * 8;
    *(bf16x8*)&Qs[r][c] = *(const bf16x8*)&akqv[(size_t)(i0 + r) * 384 + 128 + c];
  }
#pragma unroll
  for (int it = 0; it < 7; it++) {
    int q = tid + it * 256;                 // < 1792
    int r = q >> 4, c = (q & 15) * 8;
    bf16x8 v = {0, 0, 0, 0, 0, 0, 0, 0};
    if (r < nk) v = *(const bf16x8*)&akqv[(size_t)(jlo + r) * 384 + c];
    *(bf16x8*)&Ks[r][c] = v;
  }
  __syncthreads();
  for (int ff = wave; ff < 14; ff += 4) {
    int fr = ff / 7, fc = ff % 7;
    f32x4 acc = (f32x4){0.f, 0.f, 0.f, 0.f};
#pragma unroll
    for (int kk = 0; kk < 4; kk++) {
      bf16x8 a = *(const bf16x8*)&Qs[fr * 16 + lr][kk * 32 + lke];
      bf16x8 b = *(const bf16x8*)&Ks[fc * 16 + lr][kk * 32 + lke];
      acc = __builtin_amdgcn_mfma_f32_16x16x32_bf16(a, b, acc, 0, 0, 0);
    }
#pragma unroll
    for (int j = 0; j < 4; j++)
      lg[fr * 16 + (lane >> 4) * 4 + j][fc * 16 + (lane & 15)] = acc[j] * 0.06f;
  }
  __syncthreads();
#pragma unroll
  for (int q = 0; q < 8; q++) {
    int r = wave + q * 4;                   // 0..31
    int i = i0 + r;
    int c0 = lane, c1 = lane + 64;
    int e0i = i - (jlo + c0), e1i = i - (jlo + c1);
    bool v0 = (c0 < nk) && (e0i > -40) && (e0i < 40);
    bool v1 = (c1 < nk) && (e1i > -40) && (e1i < 40);
    float l0 = v0 ? lg[r][c0] : -1e30f;
    float l1 = v1 ? lg[r][min(c1, 111)] : -1e30f;
    float mx = fmaxf(l0, l1);
    for (int o = 32; o; o >>= 1) mx = fmaxf(mx, __shfl_xor(mx, o));
    float e0 = v0 ? __expf(l0 - mx) : 0.f;
    float e1 = v1 ? __expf(l1 - mx) : 0.f;
    float su = e0 + e1;
    for (int o = 32; o; o >>= 1) su += __shfl_xor(su, o);
    float inv = 1.f / su;
    int base = max(i - 39, 0);
    if (v0) Pa[(size_t)i * 79 + (jlo + c0) - base] = e0 * inv;
    if (v1) Pa[(size_t)i * 79 + (jlo + c1) - base] = e1 * inv;
  }
}

// ---------------- audio PV: one block per row i ----------------
__global__ __launch_bounds__(128) void k_pv_a(const float* __restrict__ Pa,
                                              const unsigned short* __restrict__ akqv,
                                              unsigned short* __restrict__ y0b) {
  int i = blockIdx.x, d = threadIdx.x;
  int jlo = max(i - 39, 0), jhi = min(i + 39, N_SEQ - 1);
  float acc = 0.f;
  for (int j = jlo; j <= jhi; j++)
    acc += Pa[(size_t)j * 79 + (i - max(j - 39, 0))] *
           b2f(akqv[(size_t)j * 384 + 256 + d]);
  y0b[(size_t)i * 128 + d] = f2b(acc);
}

// ---------------- head: relu(h2+b) -> LN -> dot(kd_w) -> sigmoid ----------------
__global__ __launch_bounds__(256) void k_head(const float* __restrict__ h2,
                                              const float* __restrict__ kab,
                                              const float* __restrict__ g,
                                              const float* __restrict__ b,
                                              const float* __restrict__ kdw,
                                              const float* __restrict__ kdb,
                                              float* __restrict__ out) {
  int i = blockIdx.x, tid = threadIdx.x, wave = tid >> 6, lane = tid & 63;
  __shared__ float rb[12];
  float v[4], s = 0.f, ss = 0.f;
#pragma unroll
  for (int q = 0; q < 4; q++) {
    int t = tid + q * 256;
    float x = h2[(size_t)i * 1024 + t] + kab[t];
    x = fmaxf(x, 0.f);
    v[q] = x; s += x; ss += x * x;
  }
  for (int o = 32; o; o >>= 1) { s += __shfl_xor(s, o); ss += __shfl_xor(ss, o); }
  if (!lane) { rb[wave] = s; rb[4 + wave] = ss; }
  __syncthreads();
  float S = rb[0] + rb[1] + rb[2] + rb[3];
  float SS = rb[4] + rb[5] + rb[6] + rb[7];
  float mu = S * (1.f / 1024.f);
  float var = SS * (1.f / 1024.f) - mu * mu;
  float rstd = rsqrtf(var + 1e-6f);
  float dacc = 0.f;
#pragma unroll
  for (int q = 0; q < 4; q++) {
    int t = tid + q * 256;
    dacc += ((v[q] - mu) * rstd * g[t] + b[t]) * kdw[t];
  }
  for (int o = 32; o; o >>= 1) dacc += __shfl_xor(dacc, o);
  if (!lane) rb[8 + wave] = dacc;
  __syncthreads();
  if (tid == 0) out[i] = 1.f / (1.f + __expf(-(rb[8] + rb[9] + rb[10] + rb[11] + kdb[0])));
}

extern "C" void kernel_launch(void* const* d_in, const int* in_sizes, int n_in,
                              void* d_out, int out_size, void* d_ws, size_t ws_size,
                              hipStream_t stream) {
  const float* x      = (const float*)d_in[0];
  const float* audio  = (const float*)d_in[1];
  const float* Wk     = (const float*)d_in[2];
  const float* Wq     = (const float*)d_in[3];
  const float* Wv     = (const float*)d_in[4];
  const float* Wo     = (const float*)d_in[5];
  const float* aWk    = (const float*)d_in[6];
  const float* aWq    = (const float*)d_in[7];
  const float* aWv    = (const float*)d_in[8];
  const float* aWo    = (const float*)d_in[9];
  const float* ka_w   = (const float*)d_in[10];
  const float* ka_b   = (const float*)d_in[11];
  const float* kd_w   = (const float*)d_in[12];
  const float* kd_b   = (const float*)d_in[13];
  const float* ln_y_g = (const float*)d_in[14];
  const float* ln_y_b = (const float*)d_in[15];
  const float* ln_ka_g= (const float*)d_in[16];
  const float* ln_ka_b= (const float*)d_in[17];
  const float* ln_a_g = (const float*)d_in[18];
  const float* ln_a_b = (const float*)d_in[19];
  const float* ln_a2_g= (const float*)d_in[20];
  const float* ln_a2_b= (const float*)d_in[21];

  const size_t MB = 1024ull * 1024ull;
  if (ws_size < 106 * MB) return;

  char* w = (char*)d_ws;
  unsigned short* kqv_bf  = (unsigned short*)(w);            // [4096][3072] bf16  24MB
  unsigned short* akqv_bf = (unsigned short*)(w + 24 * MB);  // [4096][384]  bf16   3MB
  float* y1    = (float*)(w + 27 * MB);                      // [4096][1024]       16MB
  float* h2    = (float*)(w + 43 * MB);                      // [4096][1024]       16MB
  float* aud32 = (float*)(w + 59 * MB);                      // [4096][128]         2MB
  float* ay1   = (float*)(w + 61 * MB);                      // [4096][128]         2MB
  float* P     = (float*)(w + 63 * MB);                      // [4096][40]        640KB
  float* Pa    = (float*)(w + 64 * MB);                      // [4096][79]        1.3MB
  unsigned short* x_bf     = (unsigned short*)(w + 66 * MB); // 8MB
  unsigned short* wkqv_bf  = (unsigned short*)(w + 74 * MB); // 6MB
  unsigned short* wo_bf    = (unsigned short*)(w + 80 * MB); // 2MB
  unsigned short* kaw_bf   = (unsigned short*)(w + 82 * MB); // 2.25MB
  unsigned short* awkqv_bf = (unsigned short*)(w + 85 * MB); // 96KB
  unsigned short* awo_bf   = (unsigned short*)(w + 86 * MB); // 32KB
  unsigned short* aud_bf   = (unsigned short*)(w + 87 * MB); // 1MB
  unsigned short* y0_bf    = (unsigned short*)(w + 88 * MB); // 8MB
  unsigned short* ay0_bf   = (unsigned short*)(w + 96 * MB); // 1MB
  unsigned short* h_bf     = (unsigned short*)(w + 97 * MB); // 9MB

  float* out0 = (float*)d_out;
  float* att  = (float*)d_out + N_SEQ;

  // zeros outside the band + out slot
  hipMemsetAsync(d_out, 0, (size_t)out_size * sizeof(float), stream);

  auto cvt = [&](const float* s, unsigned short* d, int n) {
    k_f2b<<<dim3((n / 4 + 255) / 256), 256, 0, stream>>>(s, d, n);
  };
  cvt(x, x_bf, N_SEQ * M_DIM);
  cvt(Wk, wkqv_bf, M_DIM * M_DIM);
  cvt(Wq, wkqv_bf + M_DIM * M_DIM, M_DIM * M_DIM);
  cvt(Wv, wkqv_bf + 2 * M_DIM * M_DIM, M_DIM * M_DIM);
  cvt(Wo, wo_bf, M_DIM * M_DIM);
  cvt(ka_w, kaw_bf, 1024 * H_DIM);
  cvt(aWk, awkqv_bf, A_DIM * A_DIM);
  cvt(aWq, awkqv_bf + A_DIM * A_DIM, A_DIM * A_DIM);
  cvt(aWv, awkqv_bf + 2 * A_DIM * A_DIM, A_DIM * A_DIM);
  cvt(aWo, awo_bf, A_DIM * A_DIM);

  // audio LN -> f32 (residual) + bf16 (GEMM input)
  k_ln<<<N_SEQ, 256, 0, stream>>>(audio, nullptr, ln_a2_g, ln_a2_b, aud32, aud_bf,
                                  A_DIM, A_DIM, 0);

  // fused KQV GEMMs -> bf16 only
  k_gemm<<<dim3(24, 32), 256, 0, stream>>>(x_bf, wkqv_bf, nullptr, kqv_bf, 1024, 3072);
  k_gemm<<<dim3(3, 32), 256, 0, stream>>>(aud_bf, awkqv_bf, nullptr, akqv_bf, 128, 384);

  // banded attention (tiled, MFMA) + PV (row-per-block)
  k_attn_v<<<256, 256, 0, stream>>>(kqv_bf, att, P);
  k_pv_v<<<N_SEQ, 256, 0, stream>>>(P, kqv_bf, y0_bf);
  k_attn_a<<<128, 256, 0, stream>>>(akqv_bf, Pa);
  k_pv_a<<<N_SEQ, 128, 0, stream>>>(Pa, akqv_bf, ay0_bf);

  // output projections
  k_gemm<<<dim3(8, 32), 256, 0, stream>>>(y0_bf, wo_bf, y1, nullptr, 1024, 1024);
  k_gemm<<<dim3(1, 32), 256, 0, stream>>>(ay0_bf, awo_bf, ay1, nullptr, 128, 128);

  // residual + LN -> h_bf (concat layout [4096][1152])
  k_ln<<<N_SEQ, 256, 0, stream>>>(y1, x, ln_y_g, ln_y_b, nullptr, h_bf, 1024, H_DIM, 0);
  k_ln<<<N_SEQ, 256, 0, stream>>>(ay1, aud32, ln_a_g, ln_a_b, nullptr, h_bf, 128, H_DIM, 1024);

  // MLP GEMM (K=1152)
  k_gemm<<<dim3(8, 32), 256, 0, stream>>>(h_bf, kaw_bf, h2, nullptr, H_DIM, 1024);

  // relu+bias -> LN -> dot -> sigmoid
  k_head<<<N_SEQ, 256, 0, stream>>>(h2, ka_b, ln_ka_g, ln_ka_b, kd_w, kd_b, out0);
}

// Round 5
// 234.083 us; speedup vs baseline: 1.9010x; 1.1467x over previous
//
#include <hip/hip_runtime.h>
#include <hip/hip_bf16.h>
#include <math.h>

#define N_SEQ 4096
#define M_DIM 1024
#define A_DIM 128
#define H_DIM 1152

typedef __attribute__((ext_vector_type(4))) float f32x4;
typedef __attribute__((ext_vector_type(8))) short bf16x8;
typedef __attribute__((ext_vector_type(4))) short bf16x4;

__device__ __forceinline__ unsigned short f2b(float f) {
  union { float f; unsigned int u; } v; v.f = f;
  unsigned int u = v.u;
  unsigned int r = (u + 0x7fffu + ((u >> 16) & 1u)) >> 16;
  return (unsigned short)r;
}
__device__ __forceinline__ float b2f(unsigned short u) {
  union { unsigned int i; float f; } v; v.i = ((unsigned int)u) << 16; return v.f;
}
// async global->LDS, 16B per lane; lds dest = wave-uniform base + lane*16
__device__ __forceinline__ void gload_lds16(const void* g, void* l) {
  __builtin_amdgcn_global_load_lds((const __attribute__((address_space(1))) unsigned int*)g,
                                   (__attribute__((address_space(3))) unsigned int*)l,
                                   16, 0, 0);
}

// ---------------- fused float -> bf16 convert, 10 segments in one launch ----------------
// All segment sizes are multiples of 1024 elems -> every 256-thread block lies in ONE
// segment (uniform branch); pointer selection fully unrolled (compile-time indices).
struct CvtArgs {
  const float* src[10];
  unsigned short* dst[10];
  unsigned int pfx[11];   // prefix in 4-elem groups
};
__global__ __launch_bounds__(256) void k_f2b_multi(CvtArgs a) {
  unsigned int g = blockIdx.x * 256 + threadIdx.x;
  const float* sp = a.src[0];
  unsigned short* dp = a.dst[0];
  unsigned int base = 0;
#pragma unroll
  for (int i = 1; i < 10; i++)
    if (g >= a.pfx[i]) { sp = a.src[i]; dp = a.dst[i]; base = a.pfx[i]; }
  unsigned int i4 = g - base;
  float4 f = *reinterpret_cast<const float4*>(sp + (size_t)i4 * 4);
  ushort4 o;
  o.x = f2b(f.x); o.y = f2b(f.y); o.z = f2b(f.z); o.w = f2b(f.w);
  *reinterpret_cast<ushort4*>(dp + (size_t)i4 * 4) = o;
}

// ---------------- row LayerNorm (optional residual, f32/bf16 out) ----------------
__global__ __launch_bounds__(256) void k_ln(const float* __restrict__ src,
                                            const float* __restrict__ res,
                                            const float* __restrict__ g,
                                            const float* __restrict__ b,
                                            float* __restrict__ dstf,
                                            unsigned short* __restrict__ dstb,
                                            int D, int ostride, int ooff) {
  int i = blockIdx.x, tid = threadIdx.x, wave = tid >> 6, lane = tid & 63;
  __shared__ float rb[8];
  float v[4];
  int cnt = 0;
  float s = 0.f, ss = 0.f;
  for (int t = tid; t < D; t += 256) {
    float x = src[(size_t)i * D + t];
    if (res) x += res[(size_t)i * D + t];
    v[cnt++] = x; s += x; ss += x * x;
  }
  for (int o = 32; o; o >>= 1) { s += __shfl_xor(s, o); ss += __shfl_xor(ss, o); }
  if (!lane) { rb[wave] = s; rb[4 + wave] = ss; }
  __syncthreads();
  float S = rb[0] + rb[1] + rb[2] + rb[3];
  float SS = rb[4] + rb[5] + rb[6] + rb[7];
  float mu = S / (float)D;
  float var = SS / (float)D - mu * mu;
  float rstd = rsqrtf(var + 1e-6f);
  cnt = 0;
  for (int t = tid; t < D; t += 256) {
    float o = (v[cnt++] - mu) * rstd * g[t] + b[t];
    if (dstf) dstf[(size_t)i * D + t] = o;
    if (dstb) dstb[(size_t)i * ostride + ooff + t] = f2b(o);
  }
}

// ---------------- bf16 MFMA GEMM, 2-phase pipelined (stage t+1 || compute t) ----------
// C[M][N] = A[M][K] * B[N][K]^T ; 128x128 tile, 4 waves, 4x4 frags of 16x16x32.
// Double-buffered linear LDS; ONE __syncthreads per K-step (its vmcnt/lgkm drain is the
// exact wait the 2-phase needs). XCD-bijective block swizzle (m204).
__global__ __launch_bounds__(256) void k_gemm(const unsigned short* __restrict__ A,
                                              const unsigned short* __restrict__ B,
                                              float* __restrict__ Cf,
                                              unsigned short* __restrict__ Cb,
                                              int K, int N) {
  __shared__ __attribute__((aligned(16))) unsigned short As[2][128 * 32];
  __shared__ __attribute__((aligned(16))) unsigned short Bs[2][128 * 32];
  int tid = threadIdx.x;
  // bijective XCD swizzle
  int nwg = gridDim.x * gridDim.y;
  int orig = blockIdx.y * gridDim.x + blockIdx.x;
  int q = nwg >> 3, r = nwg & 7;
  int xcd = orig & 7, idx = orig >> 3;
  int wgid = (xcd < r ? xcd * (q + 1) : r * (q + 1) + (xcd - r) * q) + idx;
  int bx = wgid % gridDim.x, by = wgid / gridDim.x;
  int row0 = by * 128, col0 = bx * 128;

  int wave = tid >> 6, lane = tid & 63;
  int wr = (wave >> 1) * 64, wc = (wave & 1) * 64;
  int lr = lane & 15;
  int lkb = (lane >> 4) * 16;          // byte offset of 8-elem k-group
  int ch = wave * 2;                   // this wave stages chunks ch, ch+1 (16 rows each)
  int srow = ch * 16 + (lane >> 2);    // row staged by this lane
  int scol = (lane & 3) * 8;           // elem col staged by this lane
  const unsigned short* ga0 = A + (size_t)(row0 + srow) * K + scol;
  const unsigned short* ga1 = ga0 + (size_t)16 * K;
  const unsigned short* gb0 = B + (size_t)(col0 + srow) * K + scol;
  const unsigned short* gb1 = gb0 + (size_t)16 * K;

  f32x4 acc[4][4];
#pragma unroll
  for (int m = 0; m < 4; m++)
#pragma unroll
    for (int n = 0; n < 4; n++) acc[m][n] = (f32x4){0.f, 0.f, 0.f, 0.f};

  auto STAGE = [&](int buf, int k0) {
    char* la = (char*)(&As[buf][0]) + ch * 1024;
    char* lb = (char*)(&Bs[buf][0]) + ch * 1024;
    gload_lds16(ga0 + k0, la);
    gload_lds16(ga1 + k0, la + 1024);
    gload_lds16(gb0 + k0, lb);
    gload_lds16(gb1 + k0, lb + 1024);
  };

  int nt = K >> 5;
  STAGE(0, 0);
  __syncthreads();                     // drain: buf0 ready
  for (int t = 0; t < nt; t++) {
    int cur = t & 1;
    if (t + 1 < nt) STAGE(cur ^ 1, (t + 1) << 5);   // overlap next-tile loads w/ compute
    const char* pa = (const char*)(&As[cur][0]) + (wr + lr) * 64 + lkb;
    const char* pb = (const char*)(&Bs[cur][0]) + (wc + lr) * 64 + lkb;
    bf16x8 af[4], bfr[4];
#pragma unroll
    for (int m = 0; m < 4; m++) af[m] = *(const bf16x8*)(pa + m * 1024);
#pragma unroll
    for (int n = 0; n < 4; n++) bfr[n] = *(const bf16x8*)(pb + n * 1024);
#pragma unroll
    for (int m = 0; m < 4; m++)
#pragma unroll
      for (int n = 0; n < 4; n++)
        acc[m][n] = __builtin_amdgcn_mfma_f32_16x16x32_bf16(af[m], bfr[n], acc[m][n], 0, 0, 0);
    __syncthreads();                   // drains next-tile vmcnt + read-done sync
  }
  int lq = lane >> 4;
#pragma unroll
  for (int m = 0; m < 4; m++)
#pragma unroll
    for (int n = 0; n < 4; n++)
#pragma unroll
      for (int j = 0; j < 4; j++) {
        int rr = row0 + wr + m * 16 + lq * 4 + j;
        int cc = col0 + wc + n * 16 + lr;
        if (Cf) Cf[(size_t)rr * N + cc] = acc[m][n][j];
        if (Cb) Cb[(size_t)rr * N + cc] = f2b(acc[m][n][j]);
      }
}

// ---------------- video banded attention: 16 Q-rows/block, MFMA QK^T ----------------
// kqv: bf16 [4096][3072] = K|Q|V. Outputs: dense att rows (band only) + compact P[4096][40].
__global__ __launch_bounds__(256) void k_attn_v(const unsigned short* __restrict__ kqv,
                                                float* __restrict__ att,
                                                float* __restrict__ P) {
  __shared__ unsigned short Qs[16][264];
  __shared__ unsigned short Ks[64][264];
  __shared__ float lg[16][64];
  int tid = threadIdx.x, wave = tid >> 6, lane = tid & 63;
  int i0 = blockIdx.x * 16;
  int jlo = max(i0 - 19, 0);
  int jhi = min(i0 + 34, N_SEQ - 1);
  int nk = jhi - jlo + 1;                  // <= 54
  int lr = lane & 15, lke = (lane >> 4) * 8;
  f32x4 acc = (f32x4){0.f, 0.f, 0.f, 0.f};
  for (int kc = 0; kc < M_DIM; kc += 256) {
    __syncthreads();
#pragma unroll
    for (int it = 0; it < 2; it++) {
      int q = tid + it * 256;              // < 512
      int r = q >> 5, c = (q & 31) * 8;
      *(bf16x8*)&Qs[r][c] =
          *(const bf16x8*)&kqv[(size_t)(i0 + r) * 3072 + 1024 + kc + c];
    }
#pragma unroll
    for (int it = 0; it < 8; it++) {
      int q = tid + it * 256;              // < 2048
      int r = q >> 5, c = (q & 31) * 8;
      bf16x8 v = {0, 0, 0, 0, 0, 0, 0, 0};
      if (r < nk) v = *(const bf16x8*)&kqv[(size_t)(jlo + r) * 3072 + kc + c];
      *(bf16x8*)&Ks[r][c] = v;
    }
    __syncthreads();
#pragma unroll
    for (int kk = 0; kk < 8; kk++) {
      bf16x8 a = *(const bf16x8*)&Qs[lr][kk * 32 + lke];
      bf16x8 b = *(const bf16x8*)&Ks[wave * 16 + lr][kk * 32 + lke];
      acc = __builtin_amdgcn_mfma_f32_16x16x32_bf16(a, b, acc, 0, 0, 0);
    }
  }
#pragma unroll
  for (int j = 0; j < 4; j++)
    lg[(lane >> 4) * 4 + j][wave * 16 + (lane & 15)] = acc[j] * 0.06f;
  __syncthreads();
#pragma unroll
  for (int q = 0; q < 4; q++) {
    int r = wave + q * 4;
    int i = i0 + r;
    int c = lane;                           // < 64
    int d = i - (jlo + c);
    bool valid = (c < nk) && (d > -20) && (d < 20);
    float v = valid ? lg[r][c] : -1e30f;
    float mx = v;
    for (int o = 32; o; o >>= 1) mx = fmaxf(mx, __shfl_xor(mx, o));
    float e = valid ? __expf(v - mx) : 0.f;
    float su = e;
    for (int o = 32; o; o >>= 1) su += __shfl_xor(su, o);
    float p = e / su;
    if (valid) {
      att[(size_t)i * N_SEQ + jlo + c] = p;
      P[(size_t)i * 40 + (jlo + c) - max(i - 19, 0)] = p;
    }
  }
}

// ---------------- video PV: one block per row i; y0[i][d] = sum_j att[j][i]*V[j][d] ----------------
__global__ __launch_bounds__(256) void k_pv_v(const float* __restrict__ P,
                                              const unsigned short* __restrict__ kqv,
                                              unsigned short* __restrict__ y0b) {
  int i = blockIdx.x, tid = threadIdx.x;
  int jlo = max(i - 19, 0), jhi = min(i + 19, N_SEQ - 1);
  int d0 = tid * 4;
  float a0 = 0.f, a1 = 0.f, a2 = 0.f, a3 = 0.f;
  for (int j = jlo; j <= jhi; j++) {
    float a = P[(size_t)j * 40 + (i - max(j - 19, 0))];        // att[j][i]
    bf16x4 v = *(const bf16x4*)&kqv[(size_t)j * 3072 + 2048 + d0];
    a0 += a * b2f((unsigned short)v[0]);
    a1 += a * b2f((unsigned short)v[1]);
    a2 += a * b2f((unsigned short)v[2]);
    a3 += a * b2f((unsigned short)v[3]);
  }
  ushort4 o;
  o.x = f2b(a0); o.y = f2b(a1); o.z = f2b(a2); o.w = f2b(a3);
  *(ushort4*)&y0b[(size_t)i * 1024 + d0] = o;
}

// ---------------- audio banded attention: 32 rows/block, MFMA, compact Pa[4096][79] ----------------
__global__ __launch_bounds__(256) void k_attn_a(const unsigned short* __restrict__ akqv,
                                                float* __restrict__ Pa) {
  __shared__ unsigned short Qs[32][136];
  __shared__ unsigned short Ks[112][136];
  __shared__ float lg[32][112];
  int tid = threadIdx.x, wave = tid >> 6, lane = tid & 63;
  int i0 = blockIdx.x * 32;
  int jlo = max(i0 - 39, 0);
  int jhi = min(i0 + 70, N_SEQ - 1);
  int nk = jhi - jlo + 1;                   // <= 110
  int lr = lane & 15, lke = (lane >> 4) * 8;
#pragma unroll
  for (int it = 0; it < 2; it++) {
    int q = tid + it * 256;                 // < 512
    int r = q >> 4, c = (q & 15) * 8;
    *(bf16x8*)&Qs[r][c] = *(const bf16x8*)&akqv[(size_t)(i0 + r) * 384 + 128 + c];
  }
#pragma unroll
  for (int it = 0; it < 7; it++) {
    int q = tid + it * 256;                 // < 1792
    int r = q >> 4, c = (q & 15) * 8;
    bf16x8 v = {0, 0, 0, 0, 0, 0, 0, 0};
    if (r < nk) v = *(const bf16x8*)&akqv[(size_t)(jlo + r) * 384 + c];
    *(bf16x8*)&Ks[r][c] = v;
  }
  __syncthreads();
  for (int ff = wave; ff < 14; ff += 4) {
    int fr = ff / 7, fc = ff % 7;
    f32x4 acc = (f32x4){0.f, 0.f, 0.f, 0.f};
#pragma unroll
    for (int kk = 0; kk < 4; kk++) {
      bf16x8 a = *(const bf16x8*)&Qs[fr * 16 + lr][kk * 32 + lke];
      bf16x8 b = *(const bf16x8*)&Ks[fc * 16 + lr][kk * 32 + lke];
      acc = __builtin_amdgcn_mfma_f32_16x16x32_bf16(a, b, acc, 0, 0, 0);
    }
#pragma unroll
    for (int j = 0; j < 4; j++)
      lg[fr * 16 + (lane >> 4) * 4 + j][fc * 16 + (lane & 15)] = acc[j] * 0.06f;
  }
  __syncthreads();
#pragma unroll
  for (int q = 0; q < 8; q++) {
    int r = wave + q * 4;                   // 0..31
    int i = i0 + r;
    int c0 = lane, c1 = lane + 64;
    int e0i = i - (jlo + c0), e1i = i - (jlo + c1);
    bool v0 = (c0 < nk) && (e0i > -40) && (e0i < 40);
    bool v1 = (c1 < nk) && (e1i > -40) && (e1i < 40);
    float l0 = v0 ? lg[r][c0] : -1e30f;
    float l1 = v1 ? lg[r][min(c1, 111)] : -1e30f;
    float mx = fmaxf(l0, l1);
    for (int o = 32; o; o >>= 1) mx = fmaxf(mx, __shfl_xor(mx, o));
    float e0 = v0 ? __expf(l0 - mx) : 0.f;
    float e1 = v1 ? __expf(l1 - mx) : 0.f;
    float su = e0 + e1;
    for (int o = 32; o; o >>= 1) su += __shfl_xor(su, o);
    float inv = 1.f / su;
    int base = max(i - 39, 0);
    if (v0) Pa[(size_t)i * 79 + (jlo + c0) - base] = e0 * inv;
    if (v1) Pa[(size_t)i * 79 + (jlo + c1) - base] = e1 * inv;
  }
}

// ---------------- audio PV: one block per row i ----------------
__global__ __launch_bounds__(128) void k_pv_a(const float* __restrict__ Pa,
                                              const unsigned short* __restrict__ akqv,
                                              unsigned short* __restrict__ y0b) {
  int i = blockIdx.x, d = threadIdx.x;
  int jlo = max(i - 39, 0), jhi = min(i + 39, N_SEQ - 1);
  float acc = 0.f;
  for (int j = jlo; j <= jhi; j++)
    acc += Pa[(size_t)j * 79 + (i - max(j - 39, 0))] *
           b2f(akqv[(size_t)j * 384 + 256 + d]);
  y0b[(size_t)i * 128 + d] = f2b(acc);
}

// ---------------- head: relu(h2+b) -> LN -> dot(kd_w) -> sigmoid ----------------
__global__ __launch_bounds__(256) void k_head(const float* __restrict__ h2,
                                              const float* __restrict__ kab,
                                              const float* __restrict__ g,
                                              const float* __restrict__ b,
                                              const float* __restrict__ kdw,
                                              const float* __restrict__ kdb,
                                              float* __restrict__ out) {
  int i = blockIdx.x, tid = threadIdx.x, wave = tid >> 6, lane = tid & 63;
  __shared__ float rb[12];
  float v[4], s = 0.f, ss = 0.f;
#pragma unroll
  for (int q = 0; q < 4; q++) {
    int t = tid + q * 256;
    float x = h2[(size_t)i * 1024 + t] + kab[t];
    x = fmaxf(x, 0.f);
    v[q] = x; s += x; ss += x * x;
  }
  for (int o = 32; o; o >>= 1) { s += __shfl_xor(s, o); ss += __shfl_xor(ss, o); }
  if (!lane) { rb[wave] = s; rb[4 + wave] = ss; }
  __syncthreads();
  float S = rb[0] + rb[1] + rb[2] + rb[3];
  float SS = rb[4] + rb[5] + rb[6] + rb[7];
  float mu = S * (1.f / 1024.f);
  float var = SS * (1.f / 1024.f) - mu * mu;
  float rstd = rsqrtf(var + 1e-6f);
  float dacc = 0.f;
#pragma unroll
  for (int q = 0; q < 4; q++) {
    int t = tid + q * 256;
    dacc += ((v[q] - mu) * rstd * g[t] + b[t]) * kdw[t];
  }
  for (int o = 32; o; o >>= 1) dacc += __shfl_xor(dacc, o);
  if (!lane) rb[8 + wave] = dacc;
  __syncthreads();
  if (tid == 0) out[i] = 1.f / (1.f + __expf(-(rb[8] + rb[9] + rb[10] + rb[11] + kdb[0])));
}

extern "C" void kernel_launch(void* const* d_in, const int* in_sizes, int n_in,
                              void* d_out, int out_size, void* d_ws, size_t ws_size,
                              hipStream_t stream) {
  const float* x      = (const float*)d_in[0];
  const float* audio  = (const float*)d_in[1];
  const float* Wk     = (const float*)d_in[2];
  const float* Wq     = (const float*)d_in[3];
  const float* Wv     = (const float*)d_in[4];
  const float* Wo     = (const float*)d_in[5];
  const float* aWk    = (const float*)d_in[6];
  const float* aWq    = (const float*)d_in[7];
  const float* aWv    = (const float*)d_in[8];
  const float* aWo    = (const float*)d_in[9];
  const float* ka_w   = (const float*)d_in[10];
  const float* ka_b   = (const float*)d_in[11];
  const float* kd_w   = (const float*)d_in[12];
  const float* kd_b   = (const float*)d_in[13];
  const float* ln_y_g = (const float*)d_in[14];
  const float* ln_y_b = (const float*)d_in[15];
  const float* ln_ka_g= (const float*)d_in[16];
  const float* ln_ka_b= (const float*)d_in[17];
  const float* ln_a_g = (const float*)d_in[18];
  const float* ln_a_b = (const float*)d_in[19];
  const float* ln_a2_g= (const float*)d_in[20];
  const float* ln_a2_b= (const float*)d_in[21];

  const size_t MB = 1024ull * 1024ull;
  if (ws_size < 106 * MB) return;

  char* w = (char*)d_ws;
  unsigned short* kqv_bf  = (unsigned short*)(w);            // [4096][3072] bf16  24MB
  unsigned short* akqv_bf = (unsigned short*)(w + 24 * MB);  // [4096][384]  bf16   3MB
  float* y1    = (float*)(w + 27 * MB);                      // [4096][1024]       16MB
  float* h2    = (float*)(w + 43 * MB);                      // [4096][1024]       16MB
  float* aud32 = (float*)(w + 59 * MB);                      // [4096][128]         2MB
  float* ay1   = (float*)(w + 61 * MB);                      // [4096][128]         2MB
  float* P     = (float*)(w + 63 * MB);                      // [4096][40]        640KB
  float* Pa    = (float*)(w + 64 * MB);                      // [4096][79]        1.3MB
  unsigned short* x_bf     = (unsigned short*)(w + 66 * MB); // 8MB
  unsigned short* wkqv_bf  = (unsigned short*)(w + 74 * MB); // 6MB
  unsigned short* wo_bf    = (unsigned short*)(w + 80 * MB); // 2MB
  unsigned short* kaw_bf   = (unsigned short*)(w + 82 * MB); // 2.25MB
  unsigned short* awkqv_bf = (unsigned short*)(w + 85 * MB); // 96KB
  unsigned short* awo_bf   = (unsigned short*)(w + 86 * MB); // 32KB
  unsigned short* aud_bf   = (unsigned short*)(w + 87 * MB); // 1MB
  unsigned short* y0_bf    = (unsigned short*)(w + 88 * MB); // 8MB
  unsigned short* ay0_bf   = (unsigned short*)(w + 96 * MB); // 1MB
  unsigned short* h_bf     = (unsigned short*)(w + 97 * MB); // 9MB

  float* out0 = (float*)d_out;
  float* att  = (float*)d_out + N_SEQ;

  // zeros outside the band + out slot
  hipMemsetAsync(d_out, 0, (size_t)out_size * sizeof(float), stream);

  // one fused conversion launch (all sizes multiples of 1024 elems)
  CvtArgs ca;
  const unsigned int MM4 = (M_DIM * M_DIM) / 4;       // 262144
  const unsigned int AA4 = (A_DIM * A_DIM) / 4;       // 4096
  ca.src[0] = x;    ca.dst[0] = x_bf;
  ca.src[1] = Wk;   ca.dst[1] = wkqv_bf;
  ca.src[2] = Wq;   ca.dst[2] = wkqv_bf + M_DIM * M_DIM;
  ca.src[3] = Wv;   ca.dst[3] = wkqv_bf + 2 * M_DIM * M_DIM;
  ca.src[4] = Wo;   ca.dst[4] = wo_bf;
  ca.src[5] = ka_w; ca.dst[5] = kaw_bf;
  ca.src[6] = aWk;  ca.dst[6] = awkqv_bf;
  ca.src[7] = aWq;  ca.dst[7] = awkqv_bf + A_DIM * A_DIM;
  ca.src[8] = aWv;  ca.dst[8] = awkqv_bf + 2 * A_DIM * A_DIM;
  ca.src[9] = aWo;  ca.dst[9] = awo_bf;
  unsigned int sz4[10] = { (N_SEQ * M_DIM) / 4, MM4, MM4, MM4, MM4,
                           (1024u * H_DIM) / 4, AA4, AA4, AA4, AA4 };
  ca.pfx[0] = 0;
  for (int i = 0; i < 10; i++) ca.pfx[i + 1] = ca.pfx[i] + sz4[i];
  k_f2b_multi<<<ca.pfx[10] / 256, 256, 0, stream>>>(ca);

  // audio LN -> f32 (residual) + bf16 (GEMM input)
  k_ln<<<N_SEQ, 256, 0, stream>>>(audio, nullptr, ln_a2_g, ln_a2_b, aud32, aud_bf,
                                  A_DIM, A_DIM, 0);

  // fused KQV GEMMs -> bf16 only
  k_gemm<<<dim3(24, 32), 256, 0, stream>>>(x_bf, wkqv_bf, nullptr, kqv_bf, 1024, 3072);
  k_gemm<<<dim3(3, 32), 256, 0, stream>>>(aud_bf, awkqv_bf, nullptr, akqv_bf, 128, 384);

  // banded attention (tiled, MFMA) + PV (row-per-block)
  k_attn_v<<<256, 256, 0, stream>>>(kqv_bf, att, P);
  k_pv_v<<<N_SEQ, 256, 0, stream>>>(P, kqv_bf, y0_bf);
  k_attn_a<<<128, 256, 0, stream>>>(akqv_bf, Pa);
  k_pv_a<<<N_SEQ, 128, 0, stream>>>(Pa, akqv_bf, ay0_bf);

  // output projections
  k_gemm<<<dim3(8, 32), 256, 0, stream>>>(y0_bf, wo_bf, y1, nullptr, 1024, 1024);
  k_gemm<<<dim3(1, 32), 256, 0, stream>>>(ay0_bf, awo_bf, ay1, nullptr, 128, 128);

  // residual + LN -> h_bf (concat layout [4096][1152])
  k_ln<<<N_SEQ, 256, 0, stream>>>(y1, x, ln_y_g, ln_y_b, nullptr, h_bf, 1024, H_DIM, 0);
  k_ln<<<N_SEQ, 256, 0, stream>>>(ay1, aud32, ln_a_g, ln_a_b, nullptr, h_bf, 128, H_DIM, 1024);

  // MLP GEMM (K=1152)
  k_gemm<<<dim3(8, 32), 256, 0, stream>>>(h_bf, kaw_bf, h2, nullptr, H_DIM, 1024);

  // relu+bias -> LN -> dot -> sigmoid
  k_head<<<N_SEQ, 256, 0, stream>>>(h2, ka_b, ln_ka_g, ln_ka_b, kd_w, kd_b, out0);
}

// Round 6
// 208.086 us; speedup vs baseline: 2.1385x; 1.1249x over previous
//
#include <hip/hip_runtime.h>
#include <hip/hip_bf16.h>
#include <math.h>

#define N_SEQ 4096
#define M_DIM 1024
#define A_DIM 128
#define H_DIM 1152

typedef __attribute__((ext_vector_type(4))) float f32x4;
typedef __attribute__((ext_vector_type(8))) short bf16x8;
typedef __attribute__((ext_vector_type(4))) short bf16x4;

__device__ __forceinline__ unsigned short f2b(float f) {
  union { float f; unsigned int u; } v; v.f = f;
  unsigned int u = v.u;
  unsigned int r = (u + 0x7fffu + ((u >> 16) & 1u)) >> 16;
  return (unsigned short)r;
}
__device__ __forceinline__ float b2f(unsigned short u) {
  union { unsigned int i; float f; } v; v.i = ((unsigned int)u) << 16; return v.f;
}
__device__ __forceinline__ void gload_lds16(const void* g, void* l) {
  __builtin_amdgcn_global_load_lds((const __attribute__((address_space(1))) unsigned int*)g,
                                   (__attribute__((address_space(3))) unsigned int*)l,
                                   16, 0, 0);
}

// ---------------- fused convert (10 segs) + d_out zero-fill (seg 10), one launch ----
struct CvtArgs {
  const float* src[10];
  unsigned short* dst[10];
  float* zf;               // zero-fill base (d_out)
  unsigned int pfx[12];    // prefix in 4-elem groups; [10]=cvt end, [11]=total
};
__global__ __launch_bounds__(256) void k_f2b_multi(CvtArgs a) {
  unsigned int g = blockIdx.x * 256 + threadIdx.x;
  if (g >= a.pfx[10]) {
    *reinterpret_cast<float4*>(a.zf + (size_t)(g - a.pfx[10]) * 4) =
        make_float4(0.f, 0.f, 0.f, 0.f);
    return;
  }
  const float* sp = a.src[0];
  unsigned short* dp = a.dst[0];
  unsigned int base = 0;
#pragma unroll
  for (int i = 1; i < 10; i++)
    if (g >= a.pfx[i]) { sp = a.src[i]; dp = a.dst[i]; base = a.pfx[i]; }
  unsigned int i4 = g - base;
  float4 f = *reinterpret_cast<const float4*>(sp + (size_t)i4 * 4);
  ushort4 o;
  o.x = f2b(f.x); o.y = f2b(f.y); o.z = f2b(f.z); o.w = f2b(f.w);
  *reinterpret_cast<ushort4*>(dp + (size_t)i4 * 4) = o;
}

// ---------------- row LayerNorm (optional residual, f32/bf16 out) ----------------
__global__ __launch_bounds__(256) void k_ln(const float* __restrict__ src,
                                            const float* __restrict__ res,
                                            const float* __restrict__ g,
                                            const float* __restrict__ b,
                                            float* __restrict__ dstf,
                                            unsigned short* __restrict__ dstb,
                                            int D, int ostride, int ooff) {
  int i = blockIdx.x, tid = threadIdx.x, wave = tid >> 6, lane = tid & 63;
  __shared__ float rb[8];
  float v[4];
  int cnt = 0;
  float s = 0.f, ss = 0.f;
  for (int t = tid; t < D; t += 256) {
    float x = src[(size_t)i * D + t];
    if (res) x += res[(size_t)i * D + t];
    v[cnt++] = x; s += x; ss += x * x;
  }
  for (int o = 32; o; o >>= 1) { s += __shfl_xor(s, o); ss += __shfl_xor(ss, o); }
  if (!lane) { rb[wave] = s; rb[4 + wave] = ss; }
  __syncthreads();
  float S = rb[0] + rb[1] + rb[2] + rb[3];
  float SS = rb[4] + rb[5] + rb[6] + rb[7];
  float mu = S / (float)D;
  float var = SS / (float)D - mu * mu;
  float rstd = rsqrtf(var + 1e-6f);
  cnt = 0;
  for (int t = tid; t < D; t += 256) {
    float o = (v[cnt++] - mu) * rstd * g[t] + b[t];
    if (dstf) dstf[(size_t)i * D + t] = o;
    if (dstb) dstb[(size_t)i * ostride + ooff + t] = f2b(o);
  }
}

// ---------------- fused LN pair -> h_bf[4096][1152] ----------------
__device__ __forceinline__ void ln_body(const float* __restrict__ src,
                                        const float* __restrict__ res,
                                        const float* __restrict__ g,
                                        const float* __restrict__ b,
                                        unsigned short* __restrict__ dstb,
                                        int D, int ooff, int i, float* rb) {
  int tid = threadIdx.x, wave = tid >> 6, lane = tid & 63;
  float v[4];
  int cnt = 0;
  float s = 0.f, ss = 0.f;
  for (int t = tid; t < D; t += 256) {
    float x = src[(size_t)i * D + t] + res[(size_t)i * D + t];
    v[cnt++] = x; s += x; ss += x * x;
  }
  for (int o = 32; o; o >>= 1) { s += __shfl_xor(s, o); ss += __shfl_xor(ss, o); }
  if (!lane) { rb[wave] = s; rb[4 + wave] = ss; }
  __syncthreads();
  float S = rb[0] + rb[1] + rb[2] + rb[3];
  float SS = rb[4] + rb[5] + rb[6] + rb[7];
  float mu = S / (float)D;
  float var = SS / (float)D - mu * mu;
  float rstd = rsqrtf(var + 1e-6f);
  cnt = 0;
  for (int t = tid; t < D; t += 256) {
    float o = (v[cnt++] - mu) * rstd * g[t] + b[t];
    dstb[(size_t)i * H_DIM + ooff + t] = f2b(o);
  }
}
__global__ __launch_bounds__(256) void k_ln2(const float* __restrict__ s1,
                                             const float* __restrict__ r1,
                                             const float* __restrict__ g1,
                                             const float* __restrict__ b1,
                                             const float* __restrict__ s2,
                                             const float* __restrict__ r2,
                                             const float* __restrict__ g2,
                                             const float* __restrict__ b2,
                                             unsigned short* __restrict__ dstb) {
  __shared__ float rb[8];
  int bid = blockIdx.x;
  if (bid < N_SEQ) ln_body(s1, r1, g1, b1, dstb, 1024, 0, bid, rb);
  else             ln_body(s2, r2, g2, b2, dstb, 128, 1024, bid - N_SEQ, rb);
}

// ---------------- bf16 MFMA GEMM, 2-phase + LDS slot-rotation swizzle ----------------
// C[M][N] = A[M][K]*B[N][K]^T; 128x128 tile, 4 waves, 4x4 frags of 16x16x32.
// Swizzle: physical 16B slot p of row r holds logical slot (p-(r>>1))&3. Staging applies
// the inverse permutation to the per-lane GLOBAL source column (gload_lds dest stays
// linear, rule #21); reads add ((lr>>1)&3) to the slot index. Spreads each 16-lane read
// phase over all 8 bank groups (2/group = free) instead of 2 (8-way).
struct GemmDesc {
  const unsigned short* A;
  const unsigned short* B;
  float* Cf;
  unsigned short* Cb;
  int K, N, gx, nb;
};
__global__ __launch_bounds__(256) void k_gemmx(GemmDesc d0, GemmDesc d1) {
  __shared__ __attribute__((aligned(16))) unsigned short As[2][128 * 32];
  __shared__ __attribute__((aligned(16))) unsigned short Bs[2][128 * 32];
  int tid = threadIdx.x;
  int bid = blockIdx.x;
  GemmDesc d = d0;
  int lid = bid;
  if (bid >= d0.nb) { d = d1; lid = bid - d0.nb; }
  // bijective XCD swizzle within segment
  int nwg = d.nb, q = nwg >> 3, r = nwg & 7;
  int xcd = lid & 7, idx = lid >> 3;
  int wgid = (xcd < r ? xcd * (q + 1) : r * (q + 1) + (xcd - r) * q) + idx;
  int bx = wgid % d.gx, by = wgid / d.gx;
  int row0 = by * 128, col0 = bx * 128;
  const int K = d.K, N = d.N;

  int wave = tid >> 6, lane = tid & 63;
  int wr = (wave >> 1) * 64, wc = (wave & 1) * 64;
  int lr = lane & 15;
  // swizzled read: physical slot = (logical + (lr>>1)) & 3
  int lkb = ((((lane >> 4) + ((lr >> 1) & 3)) & 3)) * 16;
  int ch = wave * 2;
  int srow = ch * 16 + (lane >> 2);
  // staging: phys slot (lane&3) holds logical ((lane&3) - (srow>>1)) & 3 ; (srow>>1)&3 == (lane>>3)&3
  int scol = ((((lane & 3) - ((lane >> 3) & 3)) & 3)) * 8;
  const unsigned short* ga0 = d.A + (size_t)(row0 + srow) * K + scol;
  const unsigned short* ga1 = ga0 + (size_t)16 * K;
  const unsigned short* gb0 = d.B + (size_t)(col0 + srow) * K + scol;
  const unsigned short* gb1 = gb0 + (size_t)16 * K;

  f32x4 acc[4][4];
#pragma unroll
  for (int m = 0; m < 4; m++)
#pragma unroll
    for (int n = 0; n < 4; n++) acc[m][n] = (f32x4){0.f, 0.f, 0.f, 0.f};

  auto STAGE = [&](int buf, int k0) {
    char* la = (char*)(&As[buf][0]) + ch * 1024;
    char* lb = (char*)(&Bs[buf][0]) + ch * 1024;
    gload_lds16(ga0 + k0, la);
    gload_lds16(ga1 + k0, la + 1024);
    gload_lds16(gb0 + k0, lb);
    gload_lds16(gb1 + k0, lb + 1024);
  };

  int nt = K >> 5;
  STAGE(0, 0);
  __syncthreads();
  for (int t = 0; t < nt; t++) {
    int cur = t & 1;
    if (t + 1 < nt) STAGE(cur ^ 1, (t + 1) << 5);
    const char* pa = (const char*)(&As[cur][0]) + (wr + lr) * 64 + lkb;
    const char* pb = (const char*)(&Bs[cur][0]) + (wc + lr) * 64 + lkb;
    bf16x8 af[4], bfr[4];
#pragma unroll
    for (int m = 0; m < 4; m++) af[m] = *(const bf16x8*)(pa + m * 1024);
#pragma unroll
    for (int n = 0; n < 4; n++) bfr[n] = *(const bf16x8*)(pb + n * 1024);
#pragma unroll
    for (int m = 0; m < 4; m++)
#pragma unroll
      for (int n = 0; n < 4; n++)
        acc[m][n] = __builtin_amdgcn_mfma_f32_16x16x32_bf16(af[m], bfr[n], acc[m][n], 0, 0, 0);
    __syncthreads();
  }
  int lq = lane >> 4;
#pragma unroll
  for (int m = 0; m < 4; m++)
#pragma unroll
    for (int n = 0; n < 4; n++)
#pragma unroll
      for (int j = 0; j < 4; j++) {
        int rr = row0 + wr + m * 16 + lq * 4 + j;
        int cc = col0 + wc + n * 16 + lr;
        if (d.Cf) d.Cf[(size_t)rr * N + cc] = acc[m][n][j];
        if (d.Cb) d.Cb[(size_t)rr * N + cc] = f2b(acc[m][n][j]);
      }
}

// ---------------- fused banded attention (video blocks 0-255, audio 256-383) --------
__global__ __launch_bounds__(256) void k_attn(const unsigned short* __restrict__ kqv,
                                              const unsigned short* __restrict__ akqv,
                                              float* __restrict__ att,
                                              float* __restrict__ P,
                                              float* __restrict__ Pa) {
  __shared__ __attribute__((aligned(16))) char smem[53504];
  int tid = threadIdx.x, wave = tid >> 6, lane = tid & 63;
  if (blockIdx.x < 256) {
    // ---- video: 16 Q-rows/block ----
    unsigned short(*Qs)[264] = (unsigned short(*)[264])smem;             // 8448 B
    unsigned short(*Ks)[264] = (unsigned short(*)[264])(smem + 8448);    // 33792 B
    float(*lg)[64] = (float(*)[64])(smem + 42240);                       // 4096 B
    int i0 = blockIdx.x * 16;
    int jlo = max(i0 - 19, 0);
    int jhi = min(i0 + 34, N_SEQ - 1);
    int nk = jhi - jlo + 1;                  // <= 54
    int lr = lane & 15, lke = (lane >> 4) * 8;
    f32x4 acc = (f32x4){0.f, 0.f, 0.f, 0.f};
    for (int kc = 0; kc < M_DIM; kc += 256) {
      __syncthreads();
#pragma unroll
      for (int it = 0; it < 2; it++) {
        int qq = tid + it * 256;
        int rr = qq >> 5, c = (qq & 31) * 8;
        *(bf16x8*)&Qs[rr][c] =
            *(const bf16x8*)&kqv[(size_t)(i0 + rr) * 3072 + 1024 + kc + c];
      }
#pragma unroll
      for (int it = 0; it < 8; it++) {
        int qq = tid + it * 256;
        int rr = qq >> 5, c = (qq & 31) * 8;
        bf16x8 v = {0, 0, 0, 0, 0, 0, 0, 0};
        if (rr < nk) v = *(const bf16x8*)&kqv[(size_t)(jlo + rr) * 3072 + kc + c];
        *(bf16x8*)&Ks[rr][c] = v;
      }
      __syncthreads();
#pragma unroll
      for (int kk = 0; kk < 8; kk++) {
        bf16x8 a = *(const bf16x8*)&Qs[lr][kk * 32 + lke];
        bf16x8 b = *(const bf16x8*)&Ks[wave * 16 + lr][kk * 32 + lke];
        acc = __builtin_amdgcn_mfma_f32_16x16x32_bf16(a, b, acc, 0, 0, 0);
      }
    }
#pragma unroll
    for (int j = 0; j < 4; j++)
      lg[(lane >> 4) * 4 + j][wave * 16 + (lane & 15)] = acc[j] * 0.06f;
    __syncthreads();
#pragma unroll
    for (int qq = 0; qq < 4; qq++) {
      int rr = wave + qq * 4;
      int i = i0 + rr;
      int c = lane;
      int dd = i - (jlo + c);
      bool valid = (c < nk) && (dd > -20) && (dd < 20);
      float v = valid ? lg[rr][c] : -1e30f;
      float mx = v;
      for (int o = 32; o; o >>= 1) mx = fmaxf(mx, __shfl_xor(mx, o));
      float e = valid ? __expf(v - mx) : 0.f;
      float su = e;
      for (int o = 32; o; o >>= 1) su += __shfl_xor(su, o);
      float p = e / su;
      if (valid) {
        att[(size_t)i * N_SEQ + jlo + c] = p;
        P[(size_t)i * 40 + (jlo + c) - max(i - 19, 0)] = p;
      }
    }
  } else {
    // ---- audio: 32 Q-rows/block ----
    unsigned short(*Qs)[136] = (unsigned short(*)[136])smem;             // 8704 B
    unsigned short(*Ks)[136] = (unsigned short(*)[136])(smem + 8704);    // 30464 B
    float(*lg)[112] = (float(*)[112])(smem + 39168);                     // 14336 B
    int i0 = (blockIdx.x - 256) * 32;
    int jlo = max(i0 - 39, 0);
    int jhi = min(i0 + 70, N_SEQ - 1);
    int nk = jhi - jlo + 1;                   // <= 110
    int lr = lane & 15, lke = (lane >> 4) * 8;
#pragma unroll
    for (int it = 0; it < 2; it++) {
      int qq = tid + it * 256;
      int rr = qq >> 4, c = (qq & 15) * 8;
      *(bf16x8*)&Qs[rr][c] = *(const bf16x8*)&akqv[(size_t)(i0 + rr) * 384 + 128 + c];
    }
#pragma unroll
    for (int it = 0; it < 7; it++) {
      int qq = tid + it * 256;
      int rr = qq >> 4, c = (qq & 15) * 8;
      bf16x8 v = {0, 0, 0, 0, 0, 0, 0, 0};
      if (rr < nk) v = *(const bf16x8*)&akqv[(size_t)(jlo + rr) * 384 + c];
      *(bf16x8*)&Ks[rr][c] = v;
    }
    __syncthreads();
    for (int ff = wave; ff < 14; ff += 4) {
      int fr = ff / 7, fc = ff % 7;
      f32x4 acc = (f32x4){0.f, 0.f, 0.f, 0.f};
#pragma unroll
      for (int kk = 0; kk < 4; kk++) {
        bf16x8 a = *(const bf16x8*)&Qs[fr * 16 + lr][kk * 32 + lke];
        bf16x8 b = *(const bf16x8*)&Ks[fc * 16 + lr][kk * 32 + lke];
        acc = __builtin_amdgcn_mfma_f32_16x16x32_bf16(a, b, acc, 0, 0, 0);
      }
#pragma unroll
      for (int j = 0; j < 4; j++)
        lg[fr * 16 + (lane >> 4) * 4 + j][fc * 16 + (lane & 15)] = acc[j] * 0.06f;
    }
    __syncthreads();
#pragma unroll
    for (int qq = 0; qq < 8; qq++) {
      int rr = wave + qq * 4;
      int i = i0 + rr;
      int c0 = lane, c1 = lane + 64;
      int e0i = i - (jlo + c0), e1i = i - (jlo + c1);
      bool v0 = (c0 < nk) && (e0i > -40) && (e0i < 40);
      bool v1 = (c1 < nk) && (e1i > -40) && (e1i < 40);
      float l0 = v0 ? lg[rr][c0] : -1e30f;
      float l1 = v1 ? lg[rr][min(c1, 111)] : -1e30f;
      float mx = fmaxf(l0, l1);
      for (int o = 32; o; o >>= 1) mx = fmaxf(mx, __shfl_xor(mx, o));
      float e0 = v0 ? __expf(l0 - mx) : 0.f;
      float e1 = v1 ? __expf(l1 - mx) : 0.f;
      float su = e0 + e1;
      for (int o = 32; o; o >>= 1) su += __shfl_xor(su, o);
      float inv = 1.f / su;
      int base = max(i - 39, 0);
      if (v0) Pa[(size_t)i * 79 + (jlo + c0) - base] = e0 * inv;
      if (v1) Pa[(size_t)i * 79 + (jlo + c1) - base] = e1 * inv;
    }
  }
}

// ---------------- fused PV (video blocks 0-4095; audio 4096-6143, 2 rows/block) -----
__global__ __launch_bounds__(256) void k_pv(const float* __restrict__ P,
                                            const float* __restrict__ Pa,
                                            const unsigned short* __restrict__ kqv,
                                            const unsigned short* __restrict__ akqv,
                                            unsigned short* __restrict__ y0b,
                                            unsigned short* __restrict__ ay0b) {
  int bid = blockIdx.x, tid = threadIdx.x;
  if (bid < N_SEQ) {
    int i = bid;
    int jlo = max(i - 19, 0), jhi = min(i + 19, N_SEQ - 1);
    int d0 = tid * 4;
    float a0 = 0.f, a1 = 0.f, a2 = 0.f, a3 = 0.f;
    for (int j = jlo; j <= jhi; j++) {
      float a = P[(size_t)j * 40 + (i - max(j - 19, 0))];      // att[j][i]
      bf16x4 v = *(const bf16x4*)&kqv[(size_t)j * 3072 + 2048 + d0];
      a0 += a * b2f((unsigned short)v[0]);
      a1 += a * b2f((unsigned short)v[1]);
      a2 += a * b2f((unsigned short)v[2]);
      a3 += a * b2f((unsigned short)v[3]);
    }
    ushort4 o;
    o.x = f2b(a0); o.y = f2b(a1); o.z = f2b(a2); o.w = f2b(a3);
    *(ushort4*)&y0b[(size_t)i * 1024 + d0] = o;
  } else {
    int i = (bid - N_SEQ) * 2 + (tid >> 7);
    int d = tid & 127;
    int jlo = max(i - 39, 0), jhi = min(i + 39, N_SEQ - 1);
    float acc = 0.f;
    for (int j = jlo; j <= jhi; j++)
      acc += Pa[(size_t)j * 79 + (i - max(j - 39, 0))] *
             b2f(akqv[(size_t)j * 384 + 256 + d]);
    ay0b[(size_t)i * 128 + d] = f2b(acc);
  }
}

// ---------------- head: relu(h2+b) -> LN -> dot(kd_w) -> sigmoid ----------------
__global__ __launch_bounds__(256) void k_head(const float* __restrict__ h2,
                                              const float* __restrict__ kab,
                                              const float* __restrict__ g,
                                              const float* __restrict__ b,
                                              const float* __restrict__ kdw,
                                              const float* __restrict__ kdb,
                                              float* __restrict__ out) {
  int i = blockIdx.x, tid = threadIdx.x, wave = tid >> 6, lane = tid & 63;
  __shared__ float rb[12];
  float v[4], s = 0.f, ss = 0.f;
#pragma unroll
  for (int q = 0; q < 4; q++) {
    int t = tid + q * 256;
    float x = h2[(size_t)i * 1024 + t] + kab[t];
    x = fmaxf(x, 0.f);
    v[q] = x; s += x; ss += x * x;
  }
  for (int o = 32; o; o >>= 1) { s += __shfl_xor(s, o); ss += __shfl_xor(ss, o); }
  if (!lane) { rb[wave] = s; rb[4 + wave] = ss; }
  __syncthreads();
  float S = rb[0] + rb[1] + rb[2] + rb[3];
  float SS = rb[4] + rb[5] + rb[6] + rb[7];
  float mu = S * (1.f / 1024.f);
  float var = SS * (1.f / 1024.f) - mu * mu;
  float rstd = rsqrtf(var + 1e-6f);
  float dacc = 0.f;
#pragma unroll
  for (int q = 0; q < 4; q++) {
    int t = tid + q * 256;
    dacc += ((v[q] - mu) * rstd * g[t] + b[t]) * kdw[t];
  }
  for (int o = 32; o; o >>= 1) dacc += __shfl_xor(dacc, o);
  if (!lane) rb[8 + wave] = dacc;
  __syncthreads();
  if (tid == 0) out[i] = 1.f / (1.f + __expf(-(rb[8] + rb[9] + rb[10] + rb[11] + kdb[0])));
}

extern "C" void kernel_launch(void* const* d_in, const int* in_sizes, int n_in,
                              void* d_out, int out_size, void* d_ws, size_t ws_size,
                              hipStream_t stream) {
  const float* x      = (const float*)d_in[0];
  const float* audio  = (const float*)d_in[1];
  const float* Wk     = (const float*)d_in[2];
  const float* Wq     = (const float*)d_in[3];
  const float* Wv     = (const float*)d_in[4];
  const float* Wo     = (const float*)d_in[5];
  const float* aWk    = (const float*)d_in[6];
  const float* aWq    = (const float*)d_in[7];
  const float* aWv    = (const float*)d_in[8];
  const float* aWo    = (const float*)d_in[9];
  const float* ka_w   = (const float*)d_in[10];
  const float* ka_b   = (const float*)d_in[11];
  const float* kd_w   = (const float*)d_in[12];
  const float* kd_b   = (const float*)d_in[13];
  const float* ln_y_g = (const float*)d_in[14];
  const float* ln_y_b = (const float*)d_in[15];
  const float* ln_ka_g= (const float*)d_in[16];
  const float* ln_ka_b= (const float*)d_in[17];
  const float* ln_a_g = (const float*)d_in[18];
  const float* ln_a_b = (const float*)d_in[19];
  const float* ln_a2_g= (const float*)d_in[20];
  const float* ln_a2_b= (const float*)d_in[21];

  const size_t MB = 1024ull * 1024ull;
  if (ws_size < 106 * MB) return;

  char* w = (char*)d_ws;
  unsigned short* kqv_bf  = (unsigned short*)(w);            // [4096][3072] bf16  24MB
  unsigned short* akqv_bf = (unsigned short*)(w + 24 * MB);  // [4096][384]  bf16   3MB
  float* y1    = (float*)(w + 27 * MB);                      // [4096][1024]       16MB
  float* h2    = (float*)(w + 43 * MB);                      // [4096][1024]       16MB
  float* aud32 = (float*)(w + 59 * MB);                      // [4096][128]         2MB
  float* ay1   = (float*)(w + 61 * MB);                      // [4096][128]         2MB
  float* P     = (float*)(w + 63 * MB);                      // [4096][40]        640KB
  float* Pa    = (float*)(w + 64 * MB);                      // [4096][79]        1.3MB
  unsigned short* x_bf     = (unsigned short*)(w + 66 * MB); // 8MB
  unsigned short* wkqv_bf  = (unsigned short*)(w + 74 * MB); // 6MB
  unsigned short* wo_bf    = (unsigned short*)(w + 80 * MB); // 2MB
  unsigned short* kaw_bf   = (unsigned short*)(w + 82 * MB); // 2.25MB
  unsigned short* awkqv_bf = (unsigned short*)(w + 85 * MB); // 96KB
  unsigned short* awo_bf   = (unsigned short*)(w + 86 * MB); // 32KB
  unsigned short* aud_bf   = (unsigned short*)(w + 87 * MB); // 1MB
  unsigned short* y0_bf    = (unsigned short*)(w + 88 * MB); // 8MB
  unsigned short* ay0_bf   = (unsigned short*)(w + 96 * MB); // 1MB
  unsigned short* h_bf     = (unsigned short*)(w + 97 * MB); // 9MB

  float* out0 = (float*)d_out;
  float* att  = (float*)d_out + N_SEQ;

  // fused convert + d_out zero-fill (one launch)
  CvtArgs ca;
  const unsigned int MM4 = (M_DIM * M_DIM) / 4;
  const unsigned int AA4 = (A_DIM * A_DIM) / 4;
  ca.src[0] = x;    ca.dst[0] = x_bf;
  ca.src[1] = Wk;   ca.dst[1] = wkqv_bf;
  ca.src[2] = Wq;   ca.dst[2] = wkqv_bf + M_DIM * M_DIM;
  ca.src[3] = Wv;   ca.dst[3] = wkqv_bf + 2 * M_DIM * M_DIM;
  ca.src[4] = Wo;   ca.dst[4] = wo_bf;
  ca.src[5] = ka_w; ca.dst[5] = kaw_bf;
  ca.src[6] = aWk;  ca.dst[6] = awkqv_bf;
  ca.src[7] = aWq;  ca.dst[7] = awkqv_bf + A_DIM * A_DIM;
  ca.src[8] = aWv;  ca.dst[8] = awkqv_bf + 2 * A_DIM * A_DIM;
  ca.src[9] = aWo;  ca.dst[9] = awo_bf;
  ca.zf = (float*)d_out;
  unsigned int sz4[10] = { (N_SEQ * M_DIM) / 4, MM4, MM4, MM4, MM4,
                           (1024u * H_DIM) / 4, AA4, AA4, AA4, AA4 };
  ca.pfx[0] = 0;
  for (int i = 0; i < 10; i++) ca.pfx[i + 1] = ca.pfx[i] + sz4[i];
  ca.pfx[11] = ca.pfx[10] + (unsigned int)(out_size / 4);
  k_f2b_multi<<<(ca.pfx[11] + 255) / 256, 256, 0, stream>>>(ca);

  // audio input LN -> f32 (residual) + bf16 (GEMM input)
  k_ln<<<N_SEQ, 256, 0, stream>>>(audio, nullptr, ln_a2_g, ln_a2_b, aud32, aud_bf,
                                  A_DIM, A_DIM, 0);

  // KQV + aKQV GEMMs (one launch)
  GemmDesc dk { x_bf,   wkqv_bf,  nullptr, kqv_bf,  1024, 3072, 24, 768 };
  GemmDesc da { aud_bf, awkqv_bf, nullptr, akqv_bf, 128,  384,  3,  96  };
  k_gemmx<<<dk.nb + da.nb, 256, 0, stream>>>(dk, da);

  // fused banded attention + fused PV
  k_attn<<<384, 256, 0, stream>>>(kqv_bf, akqv_bf, att, P, Pa);
  k_pv<<<N_SEQ + N_SEQ / 2, 256, 0, stream>>>(P, Pa, kqv_bf, akqv_bf, y0_bf, ay0_bf);

  // Wo + aWo projections (one launch)
  GemmDesc dw { y0_bf,  wo_bf,  y1,  nullptr, 1024, 1024, 8, 256 };
  GemmDesc dv { ay0_bf, awo_bf, ay1, nullptr, 128,  128,  1, 32  };
  k_gemmx<<<dw.nb + dv.nb, 256, 0, stream>>>(dw, dv);

  // fused residual+LN pair -> h_bf [4096][1152]
  k_ln2<<<2 * N_SEQ, 256, 0, stream>>>(y1, x, ln_y_g, ln_y_b,
                                       ay1, aud32, ln_a_g, ln_a_b, h_bf);

  // MLP GEMM (K=1152)
  GemmDesc dm { h_bf, kaw_bf, h2, nullptr, 1152, 1024, 8, 256 };
  GemmDesc dz { nullptr, nullptr, nullptr, nullptr, 32, 128, 1, 0 };
  k_gemmx<<<dm.nb, 256, 0, stream>>>(dm, dz);

  // relu+bias -> LN -> dot -> sigmoid
  k_head<<<N_SEQ, 256, 0, stream>>>(h2, ka_b, ln_ka_g, ln_ka_b, kd_w, kd_b, out0);
}

// Round 7
// 179.353 us; speedup vs baseline: 2.4811x; 1.1602x over previous
//
#include <hip/hip_runtime.h>
#include <hip/hip_bf16.h>
#include <math.h>

#define N_SEQ 4096
#define M_DIM 1024
#define A_DIM 128
#define H_DIM 1152

typedef __attribute__((ext_vector_type(4))) float f32x4;
typedef __attribute__((ext_vector_type(8))) short bf16x8;
typedef __attribute__((ext_vector_type(4))) short bf16x4;

__device__ __forceinline__ unsigned short f2b(float f) {
  union { float f; unsigned int u; } v; v.f = f;
  unsigned int u = v.u;
  unsigned int r = (u + 0x7fffu + ((u >> 16) & 1u)) >> 16;
  return (unsigned short)r;
}
__device__ __forceinline__ float b2f(unsigned short u) {
  union { unsigned int i; float f; } v; v.i = ((unsigned int)u) << 16; return v.f;
}
__device__ __forceinline__ void gload_lds16(const void* g, void* l) {
  __builtin_amdgcn_global_load_lds((const __attribute__((address_space(1))) unsigned int*)g,
                                   (__attribute__((address_space(3))) unsigned int*)l,
                                   16, 0, 0);
}

// ---------------- fused convert (10 segs) + d_out zero-fill (seg 10), one launch ----
struct CvtArgs {
  const float* src[10];
  unsigned short* dst[10];
  float* zf;               // zero-fill base (d_out)
  unsigned int pfx[12];    // prefix in 4-elem groups; [10]=cvt end, [11]=total
};
__global__ __launch_bounds__(256) void k_f2b_multi(CvtArgs a) {
  unsigned int g = blockIdx.x * 256 + threadIdx.x;
  if (g >= a.pfx[10]) {
    *reinterpret_cast<float4*>(a.zf + (size_t)(g - a.pfx[10]) * 4) =
        make_float4(0.f, 0.f, 0.f, 0.f);
    return;
  }
  const float* sp = a.src[0];
  unsigned short* dp = a.dst[0];
  unsigned int base = 0;
#pragma unroll
  for (int i = 1; i < 10; i++)
    if (g >= a.pfx[i]) { sp = a.src[i]; dp = a.dst[i]; base = a.pfx[i]; }
  unsigned int i4 = g - base;
  float4 f = *reinterpret_cast<const float4*>(sp + (size_t)i4 * 4);
  ushort4 o;
  o.x = f2b(f.x); o.y = f2b(f.y); o.z = f2b(f.z); o.w = f2b(f.w);
  *reinterpret_cast<ushort4*>(dp + (size_t)i4 * 4) = o;
}

// ---------------- row LayerNorm (optional residual, f32/bf16 out) ----------------
__global__ __launch_bounds__(256) void k_ln(const float* __restrict__ src,
                                            const float* __restrict__ res,
                                            const float* __restrict__ g,
                                            const float* __restrict__ b,
                                            float* __restrict__ dstf,
                                            unsigned short* __restrict__ dstb,
                                            int D, int ostride, int ooff) {
  int i = blockIdx.x, tid = threadIdx.x, wave = tid >> 6, lane = tid & 63;
  __shared__ float rb[8];
  float v[4];
  int cnt = 0;
  float s = 0.f, ss = 0.f;
  for (int t = tid; t < D; t += 256) {
    float x = src[(size_t)i * D + t];
    if (res) x += res[(size_t)i * D + t];
    v[cnt++] = x; s += x; ss += x * x;
  }
  for (int o = 32; o; o >>= 1) { s += __shfl_xor(s, o); ss += __shfl_xor(ss, o); }
  if (!lane) { rb[wave] = s; rb[4 + wave] = ss; }
  __syncthreads();
  float S = rb[0] + rb[1] + rb[2] + rb[3];
  float SS = rb[4] + rb[5] + rb[6] + rb[7];
  float mu = S / (float)D;
  float var = SS / (float)D - mu * mu;
  float rstd = rsqrtf(var + 1e-6f);
  cnt = 0;
  for (int t = tid; t < D; t += 256) {
    float o = (v[cnt++] - mu) * rstd * g[t] + b[t];
    if (dstf) dstf[(size_t)i * D + t] = o;
    if (dstb) dstb[(size_t)i * ostride + ooff + t] = f2b(o);
  }
}

// ---------------- fused LN pair -> h_bf[4096][1152] ----------------
__device__ __forceinline__ void ln_body(const float* __restrict__ src,
                                        const float* __restrict__ res,
                                        const float* __restrict__ g,
                                        const float* __restrict__ b,
                                        unsigned short* __restrict__ dstb,
                                        int D, int ooff, int i, float* rb) {
  int tid = threadIdx.x, wave = tid >> 6, lane = tid & 63;
  float v[4];
  int cnt = 0;
  float s = 0.f, ss = 0.f;
  for (int t = tid; t < D; t += 256) {
    float x = src[(size_t)i * D + t] + res[(size_t)i * D + t];
    v[cnt++] = x; s += x; ss += x * x;
  }
  for (int o = 32; o; o >>= 1) { s += __shfl_xor(s, o); ss += __shfl_xor(ss, o); }
  if (!lane) { rb[wave] = s; rb[4 + wave] = ss; }
  __syncthreads();
  float S = rb[0] + rb[1] + rb[2] + rb[3];
  float SS = rb[4] + rb[5] + rb[6] + rb[7];
  float mu = S / (float)D;
  float var = SS / (float)D - mu * mu;
  float rstd = rsqrtf(var + 1e-6f);
  cnt = 0;
  for (int t = tid; t < D; t += 256) {
    float o = (v[cnt++] - mu) * rstd * g[t] + b[t];
    dstb[(size_t)i * H_DIM + ooff + t] = f2b(o);
  }
}
__global__ __launch_bounds__(256) void k_ln2(const float* __restrict__ s1,
                                             const float* __restrict__ r1,
                                             const float* __restrict__ g1,
                                             const float* __restrict__ b1,
                                             const float* __restrict__ s2,
                                             const float* __restrict__ r2,
                                             const float* __restrict__ g2,
                                             const float* __restrict__ b2,
                                             unsigned short* __restrict__ dstb) {
  __shared__ float rb[8];
  int bid = blockIdx.x;
  if (bid < N_SEQ) ln_body(s1, r1, g1, b1, dstb, 1024, 0, bid, rb);
  else             ln_body(s2, r2, g2, b2, dstb, 128, 1024, bid - N_SEQ, rb);
}

// ---------------- bf16 MFMA GEMM, 2-phase + LDS slot-rotation swizzle ----------------
struct GemmDesc {
  const unsigned short* A;
  const unsigned short* B;
  float* Cf;
  unsigned short* Cb;
  int K, N, gx, nb;
};
__global__ __launch_bounds__(256) void k_gemmx(GemmDesc d0, GemmDesc d1) {
  __shared__ __attribute__((aligned(16))) unsigned short As[2][128 * 32];
  __shared__ __attribute__((aligned(16))) unsigned short Bs[2][128 * 32];
  int tid = threadIdx.x;
  int bid = blockIdx.x;
  GemmDesc d = d0;
  int lid = bid;
  if (bid >= d0.nb) { d = d1; lid = bid - d0.nb; }
  // bijective XCD swizzle within segment
  int nwg = d.nb, q = nwg >> 3, r = nwg & 7;
  int xcd = lid & 7, idx = lid >> 3;
  int wgid = (xcd < r ? xcd * (q + 1) : r * (q + 1) + (xcd - r) * q) + idx;
  int bx = wgid % d.gx, by = wgid / d.gx;
  int row0 = by * 128, col0 = bx * 128;
  const int K = d.K, N = d.N;

  int wave = tid >> 6, lane = tid & 63;
  int wr = (wave >> 1) * 64, wc = (wave & 1) * 64;
  int lr = lane & 15;
  int lkb = ((((lane >> 4) + ((lr >> 1) & 3)) & 3)) * 16;
  int ch = wave * 2;
  int srow = ch * 16 + (lane >> 2);
  int scol = ((((lane & 3) - ((lane >> 3) & 3)) & 3)) * 8;
  const unsigned short* ga0 = d.A + (size_t)(row0 + srow) * K + scol;
  const unsigned short* ga1 = ga0 + (size_t)16 * K;
  const unsigned short* gb0 = d.B + (size_t)(col0 + srow) * K + scol;
  const unsigned short* gb1 = gb0 + (size_t)16 * K;

  f32x4 acc[4][4];
#pragma unroll
  for (int m = 0; m < 4; m++)
#pragma unroll
    for (int n = 0; n < 4; n++) acc[m][n] = (f32x4){0.f, 0.f, 0.f, 0.f};

  auto STAGE = [&](int buf, int k0) {
    char* la = (char*)(&As[buf][0]) + ch * 1024;
    char* lb = (char*)(&Bs[buf][0]) + ch * 1024;
    gload_lds16(ga0 + k0, la);
    gload_lds16(ga1 + k0, la + 1024);
    gload_lds16(gb0 + k0, lb);
    gload_lds16(gb1 + k0, lb + 1024);
  };

  int nt = K >> 5;
  STAGE(0, 0);
  __syncthreads();
  for (int t = 0; t < nt; t++) {
    int cur = t & 1;
    if (t + 1 < nt) STAGE(cur ^ 1, (t + 1) << 5);
    const char* pa = (const char*)(&As[cur][0]) + (wr + lr) * 64 + lkb;
    const char* pb = (const char*)(&Bs[cur][0]) + (wc + lr) * 64 + lkb;
    bf16x8 af[4], bfr[4];
#pragma unroll
    for (int m = 0; m < 4; m++) af[m] = *(const bf16x8*)(pa + m * 1024);
#pragma unroll
    for (int n = 0; n < 4; n++) bfr[n] = *(const bf16x8*)(pb + n * 1024);
#pragma unroll
    for (int m = 0; m < 4; m++)
#pragma unroll
      for (int n = 0; n < 4; n++)
        acc[m][n] = __builtin_amdgcn_mfma_f32_16x16x32_bf16(af[m], bfr[n], acc[m][n], 0, 0, 0);
    __syncthreads();
  }
  int lq = lane >> 4;
#pragma unroll
  for (int m = 0; m < 4; m++)
#pragma unroll
    for (int n = 0; n < 4; n++)
#pragma unroll
      for (int j = 0; j < 4; j++) {
        int rr = row0 + wr + m * 16 + lq * 4 + j;
        int cc = col0 + wc + n * 16 + lr;
        if (d.Cf) d.Cf[(size_t)rr * N + cc] = acc[m][n][j];
        if (d.Cb) d.Cb[(size_t)rr * N + cc] = f2b(acc[m][n][j]);
      }
}

// ---------------- fused banded attention (video blocks 0-255, audio 256-383) --------
__global__ __launch_bounds__(256) void k_attn(const unsigned short* __restrict__ kqv,
                                              const unsigned short* __restrict__ akqv,
                                              float* __restrict__ att,
                                              float* __restrict__ P,
                                              float* __restrict__ Pa) {
  __shared__ __attribute__((aligned(16))) char smem[53504];
  int tid = threadIdx.x, wave = tid >> 6, lane = tid & 63;
  if (blockIdx.x < 256) {
    unsigned short(*Qs)[264] = (unsigned short(*)[264])smem;
    unsigned short(*Ks)[264] = (unsigned short(*)[264])(smem + 8448);
    float(*lg)[64] = (float(*)[64])(smem + 42240);
    int i0 = blockIdx.x * 16;
    int jlo = max(i0 - 19, 0);
    int jhi = min(i0 + 34, N_SEQ - 1);
    int nk = jhi - jlo + 1;                  // <= 54
    int lr = lane & 15, lke = (lane >> 4) * 8;
    f32x4 acc = (f32x4){0.f, 0.f, 0.f, 0.f};
    for (int kc = 0; kc < M_DIM; kc += 256) {
      __syncthreads();
#pragma unroll
      for (int it = 0; it < 2; it++) {
        int qq = tid + it * 256;
        int rr = qq >> 5, c = (qq & 31) * 8;
        *(bf16x8*)&Qs[rr][c] =
            *(const bf16x8*)&kqv[(size_t)(i0 + rr) * 3072 + 1024 + kc + c];
      }
#pragma unroll
      for (int it = 0; it < 8; it++) {
        int qq = tid + it * 256;
        int rr = qq >> 5, c = (qq & 31) * 8;
        bf16x8 v = {0, 0, 0, 0, 0, 0, 0, 0};
        if (rr < nk) v = *(const bf16x8*)&kqv[(size_t)(jlo + rr) * 3072 + kc + c];
        *(bf16x8*)&Ks[rr][c] = v;
      }
      __syncthreads();
#pragma unroll
      for (int kk = 0; kk < 8; kk++) {
        bf16x8 a = *(const bf16x8*)&Qs[lr][kk * 32 + lke];
        bf16x8 b = *(const bf16x8*)&Ks[wave * 16 + lr][kk * 32 + lke];
        acc = __builtin_amdgcn_mfma_f32_16x16x32_bf16(a, b, acc, 0, 0, 0);
      }
    }
#pragma unroll
    for (int j = 0; j < 4; j++)
      lg[(lane >> 4) * 4 + j][wave * 16 + (lane & 15)] = acc[j] * 0.06f;
    __syncthreads();
#pragma unroll
    for (int qq = 0; qq < 4; qq++) {
      int rr = wave + qq * 4;
      int i = i0 + rr;
      int c = lane;
      int dd = i - (jlo + c);
      bool valid = (c < nk) && (dd > -20) && (dd < 20);
      float v = valid ? lg[rr][c] : -1e30f;
      float mx = v;
      for (int o = 32; o; o >>= 1) mx = fmaxf(mx, __shfl_xor(mx, o));
      float e = valid ? __expf(v - mx) : 0.f;
      float su = e;
      for (int o = 32; o; o >>= 1) su += __shfl_xor(su, o);
      float p = e / su;
      if (valid) {
        att[(size_t)i * N_SEQ + jlo + c] = p;
        P[(size_t)i * 40 + (jlo + c) - max(i - 19, 0)] = p;
      }
    }
  } else {
    unsigned short(*Qs)[136] = (unsigned short(*)[136])smem;
    unsigned short(*Ks)[136] = (unsigned short(*)[136])(smem + 8704);
    float(*lg)[112] = (float(*)[112])(smem + 39168);
    int i0 = (blockIdx.x - 256) * 32;
    int jlo = max(i0 - 39, 0);
    int jhi = min(i0 + 70, N_SEQ - 1);
    int nk = jhi - jlo + 1;                   // <= 110
    int lr = lane & 15, lke = (lane >> 4) * 8;
#pragma unroll
    for (int it = 0; it < 2; it++) {
      int qq = tid + it * 256;
      int rr = qq >> 4, c = (qq & 15) * 8;
      *(bf16x8*)&Qs[rr][c] = *(const bf16x8*)&akqv[(size_t)(i0 + rr) * 384 + 128 + c];
    }
#pragma unroll
    for (int it = 0; it < 7; it++) {
      int qq = tid + it * 256;
      int rr = qq >> 4, c = (qq & 15) * 8;
      bf16x8 v = {0, 0, 0, 0, 0, 0, 0, 0};
      if (rr < nk) v = *(const bf16x8*)&akqv[(size_t)(jlo + rr) * 384 + c];
      *(bf16x8*)&Ks[rr][c] = v;
    }
    __syncthreads();
    for (int ff = wave; ff < 14; ff += 4) {
      int fr = ff / 7, fc = ff % 7;
      f32x4 acc = (f32x4){0.f, 0.f, 0.f, 0.f};
#pragma unroll
      for (int kk = 0; kk < 4; kk++) {
        bf16x8 a = *(const bf16x8*)&Qs[fr * 16 + lr][kk * 32 + lke];
        bf16x8 b = *(const bf16x8*)&Ks[fc * 16 + lr][kk * 32 + lke];
        acc = __builtin_amdgcn_mfma_f32_16x16x32_bf16(a, b, acc, 0, 0, 0);
      }
#pragma unroll
      for (int j = 0; j < 4; j++)
        lg[fr * 16 + (lane >> 4) * 4 + j][fc * 16 + (lane & 15)] = acc[j] * 0.06f;
    }
    __syncthreads();
#pragma unroll
    for (int qq = 0; qq < 8; qq++) {
      int rr = wave + qq * 4;
      int i = i0 + rr;
      int c0 = lane, c1 = lane + 64;
      int e0i = i - (jlo + c0), e1i = i - (jlo + c1);
      bool v0 = (c0 < nk) && (e0i > -40) && (e0i < 40);
      bool v1 = (c1 < nk) && (e1i > -40) && (e1i < 40);
      float l0 = v0 ? lg[rr][c0] : -1e30f;
      float l1 = v1 ? lg[rr][min(c1, 111)] : -1e30f;
      float mx = fmaxf(l0, l1);
      for (int o = 32; o; o >>= 1) mx = fmaxf(mx, __shfl_xor(mx, o));
      float e0 = v0 ? __expf(l0 - mx) : 0.f;
      float e1 = v1 ? __expf(l1 - mx) : 0.f;
      float su = e0 + e1;
      for (int o = 32; o; o >>= 1) su += __shfl_xor(su, o);
      float inv = 1.f / su;
      int base = max(i - 39, 0);
      if (v0) Pa[(size_t)i * 79 + (jlo + c0) - base] = e0 * inv;
      if (v1) Pa[(size_t)i * 79 + (jlo + c1) - base] = e1 * inv;
    }
  }
}

// ---------------- fused PV, XCD-chunked + LDS-staged P + pipelined loops -----------
// audio blocks 0-2047 (2 rows each, longer work first), video blocks 2048-6143.
// XCD k owns contiguous rows [k*512, (k+1)*512) in both segments -> V slab L2-resident.
__global__ __launch_bounds__(256) void k_pv(const float* __restrict__ P,
                                            const float* __restrict__ Pa,
                                            const unsigned short* __restrict__ kqv,
                                            const unsigned short* __restrict__ akqv,
                                            unsigned short* __restrict__ y0b,
                                            unsigned short* __restrict__ ay0b) {
  int bid = blockIdx.x, tid = threadIdx.x;
  if (bid < 2048) {
    // ---- audio: 2 rows/block ----
    __shared__ float pa_s[2][80];
    int xcd = bid & 7, idx = bid >> 3;
    int half = tid >> 7, d = tid & 127;
    int i = (xcd * 256 + idx) * 2 + half;
    int jlo = max(i - 39, 0), jhi = min(i + 39, N_SEQ - 1);
    int nj = jhi - jlo + 1;                  // <= 79
    if (d < nj)
      pa_s[half][d] = Pa[(size_t)(jlo + d) * 79 + (i - max(jlo + d - 39, 0))];
    __syncthreads();
    float acc = 0.f;
#pragma unroll 8
    for (int t = 0; t < 79; t++) {
      bool v = t < nj;
      int j = v ? (jlo + t) : jhi;
      float a = v ? pa_s[half][t] : 0.f;
      acc += a * b2f(akqv[(size_t)j * 384 + 256 + d]);
    }
    ay0b[(size_t)i * 128 + d] = f2b(acc);
  } else {
    // ---- video: 1 row/block, 4 dims/thread ----
    __shared__ float pv_s[40];
    int vb = bid - 2048;
    int xcd = vb & 7, idx = vb >> 3;
    int i = xcd * 512 + idx;
    int jlo = max(i - 19, 0), jhi = min(i + 19, N_SEQ - 1);
    int nj = jhi - jlo + 1;                  // <= 39
    if (tid < nj)
      pv_s[tid] = P[(size_t)(jlo + tid) * 40 + (i - max(jlo + tid - 19, 0))];
    __syncthreads();
    int d0 = tid * 4;
    float a0 = 0.f, a1 = 0.f, a2 = 0.f, a3 = 0.f;
#pragma unroll
    for (int t = 0; t < 39; t++) {
      bool v = t < nj;
      int j = v ? (jlo + t) : jhi;
      float a = v ? pv_s[t] : 0.f;
      bf16x4 vv = *(const bf16x4*)&kqv[(size_t)j * 3072 + 2048 + d0];
      a0 += a * b2f((unsigned short)vv[0]);
      a1 += a * b2f((unsigned short)vv[1]);
      a2 += a * b2f((unsigned short)vv[2]);
      a3 += a * b2f((unsigned short)vv[3]);
    }
    ushort4 o;
    o.x = f2b(a0); o.y = f2b(a1); o.z = f2b(a2); o.w = f2b(a3);
    *(ushort4*)&y0b[(size_t)i * 1024 + d0] = o;
  }
}

// ---------------- head: relu(h2+b) -> LN -> dot(kd_w) -> sigmoid ----------------
__global__ __launch_bounds__(256) void k_head(const float* __restrict__ h2,
                                              const float* __restrict__ kab,
                                              const float* __restrict__ g,
                                              const float* __restrict__ b,
                                              const float* __restrict__ kdw,
                                              const float* __restrict__ kdb,
                                              float* __restrict__ out) {
  int i = blockIdx.x, tid = threadIdx.x, wave = tid >> 6, lane = tid & 63;
  __shared__ float rb[12];
  float v[4], s = 0.f, ss = 0.f;
#pragma unroll
  for (int q = 0; q < 4; q++) {
    int t = tid + q * 256;
    float x = h2[(size_t)i * 1024 + t] + kab[t];
    x = fmaxf(x, 0.f);
    v[q] = x; s += x; ss += x * x;
  }
  for (int o = 32; o; o >>= 1) { s += __shfl_xor(s, o); ss += __shfl_xor(ss, o); }
  if (!lane) { rb[wave] = s; rb[4 + wave] = ss; }
  __syncthreads();
  float S = rb[0] + rb[1] + rb[2] + rb[3];
  float SS = rb[4] + rb[5] + rb[6] + rb[7];
  float mu = S * (1.f / 1024.f);
  float var = SS * (1.f / 1024.f) - mu * mu;
  float rstd = rsqrtf(var + 1e-6f);
  float dacc = 0.f;
#pragma unroll
  for (int q = 0; q < 4; q++) {
    int t = tid + q * 256;
    dacc += ((v[q] - mu) * rstd * g[t] + b[t]) * kdw[t];
  }
  for (int o = 32; o; o >>= 1) dacc += __shfl_xor(dacc, o);
  if (!lane) rb[8 + wave] = dacc;
  __syncthreads();
  if (tid == 0) out[i] = 1.f / (1.f + __expf(-(rb[8] + rb[9] + rb[10] + rb[11] + kdb[0])));
}

extern "C" void kernel_launch(void* const* d_in, const int* in_sizes, int n_in,
                              void* d_out, int out_size, void* d_ws, size_t ws_size,
                              hipStream_t stream) {
  const float* x      = (const float*)d_in[0];
  const float* audio  = (const float*)d_in[1];
  const float* Wk     = (const float*)d_in[2];
  const float* Wq     = (const float*)d_in[3];
  const float* Wv     = (const float*)d_in[4];
  const float* Wo     = (const float*)d_in[5];
  const float* aWk    = (const float*)d_in[6];
  const float* aWq    = (const float*)d_in[7];
  const float* aWv    = (const float*)d_in[8];
  const float* aWo    = (const float*)d_in[9];
  const float* ka_w   = (const float*)d_in[10];
  const float* ka_b   = (const float*)d_in[11];
  const float* kd_w   = (const float*)d_in[12];
  const float* kd_b   = (const float*)d_in[13];
  const float* ln_y_g = (const float*)d_in[14];
  const float* ln_y_b = (const float*)d_in[15];
  const float* ln_ka_g= (const float*)d_in[16];
  const float* ln_ka_b= (const float*)d_in[17];
  const float* ln_a_g = (const float*)d_in[18];
  const float* ln_a_b = (const float*)d_in[19];
  const float* ln_a2_g= (const float*)d_in[20];
  const float* ln_a2_b= (const float*)d_in[21];

  const size_t MB = 1024ull * 1024ull;
  if (ws_size < 106 * MB) return;

  char* w = (char*)d_ws;
  unsigned short* kqv_bf  = (unsigned short*)(w);            // [4096][3072] bf16  24MB
  unsigned short* akqv_bf = (unsigned short*)(w + 24 * MB);  // [4096][384]  bf16   3MB
  float* y1    = (float*)(w + 27 * MB);                      // [4096][1024]       16MB
  float* h2    = (float*)(w + 43 * MB);                      // [4096][1024]       16MB
  float* aud32 = (float*)(w + 59 * MB);                      // [4096][128]         2MB
  float* ay1   = (float*)(w + 61 * MB);                      // [4096][128]         2MB
  float* P     = (float*)(w + 63 * MB);                      // [4096][40]        640KB
  float* Pa    = (float*)(w + 64 * MB);                      // [4096][79]        1.3MB
  unsigned short* x_bf     = (unsigned short*)(w + 66 * MB); // 8MB
  unsigned short* wkqv_bf  = (unsigned short*)(w + 74 * MB); // 6MB
  unsigned short* wo_bf    = (unsigned short*)(w + 80 * MB); // 2MB
  unsigned short* kaw_bf   = (unsigned short*)(w + 82 * MB); // 2.25MB
  unsigned short* awkqv_bf = (unsigned short*)(w + 85 * MB); // 96KB
  unsigned short* awo_bf   = (unsigned short*)(w + 86 * MB); // 32KB
  unsigned short* aud_bf   = (unsigned short*)(w + 87 * MB); // 1MB
  unsigned short* y0_bf    = (unsigned short*)(w + 88 * MB); // 8MB
  unsigned short* ay0_bf   = (unsigned short*)(w + 96 * MB); // 1MB
  unsigned short* h_bf     = (unsigned short*)(w + 97 * MB); // 9MB

  float* out0 = (float*)d_out;
  float* att  = (float*)d_out + N_SEQ;

  // fused convert + d_out zero-fill (one launch)
  CvtArgs ca;
  const unsigned int MM4 = (M_DIM * M_DIM) / 4;
  const unsigned int AA4 = (A_DIM * A_DIM) / 4;
  ca.src[0] = x;    ca.dst[0] = x_bf;
  ca.src[1] = Wk;   ca.dst[1] = wkqv_bf;
  ca.src[2] = Wq;   ca.dst[2] = wkqv_bf + M_DIM * M_DIM;
  ca.src[3] = Wv;   ca.dst[3] = wkqv_bf + 2 * M_DIM * M_DIM;
  ca.src[4] = Wo;   ca.dst[4] = wo_bf;
  ca.src[5] = ka_w; ca.dst[5] = kaw_bf;
  ca.src[6] = aWk;  ca.dst[6] = awkqv_bf;
  ca.src[7] = aWq;  ca.dst[7] = awkqv_bf + A_DIM * A_DIM;
  ca.src[8] = aWv;  ca.dst[8] = awkqv_bf + 2 * A_DIM * A_DIM;
  ca.src[9] = aWo;  ca.dst[9] = awo_bf;
  ca.zf = (float*)d_out;
  unsigned int sz4[10] = { (N_SEQ * M_DIM) / 4, MM4, MM4, MM4, MM4,
                           (1024u * H_DIM) / 4, AA4, AA4, AA4, AA4 };
  ca.pfx[0] = 0;
  for (int i = 0; i < 10; i++) ca.pfx[i + 1] = ca.pfx[i] + sz4[i];
  ca.pfx[11] = ca.pfx[10] + (unsigned int)(out_size / 4);
  k_f2b_multi<<<(ca.pfx[11] + 255) / 256, 256, 0, stream>>>(ca);

  // audio input LN -> f32 (residual) + bf16 (GEMM input)
  k_ln<<<N_SEQ, 256, 0, stream>>>(audio, nullptr, ln_a2_g, ln_a2_b, aud32, aud_bf,
                                  A_DIM, A_DIM, 0);

  // KQV + aKQV GEMMs (one launch)
  GemmDesc dk { x_bf,   wkqv_bf,  nullptr, kqv_bf,  1024, 3072, 24, 768 };
  GemmDesc da { aud_bf, awkqv_bf, nullptr, akqv_bf, 128,  384,  3,  96  };
  k_gemmx<<<dk.nb + da.nb, 256, 0, stream>>>(dk, da);

  // fused banded attention + fused PV (audio-first, XCD-chunked)
  k_attn<<<384, 256, 0, stream>>>(kqv_bf, akqv_bf, att, P, Pa);
  k_pv<<<2048 + N_SEQ, 256, 0, stream>>>(P, Pa, kqv_bf, akqv_bf, y0_bf, ay0_bf);

  // Wo + aWo projections (one launch)
  GemmDesc dw { y0_bf,  wo_bf,  y1,  nullptr, 1024, 1024, 8, 256 };
  GemmDesc dv { ay0_bf, awo_bf, ay1, nullptr, 128,  128,  1, 32  };
  k_gemmx<<<dw.nb + dv.nb, 256, 0, stream>>>(dw, dv);

  // fused residual+LN pair -> h_bf [4096][1152]
  k_ln2<<<2 * N_SEQ, 256, 0, stream>>>(y1, x, ln_y_g, ln_y_b,
                                       ay1, aud32, ln_a_g, ln_a_b, h_bf);

  // MLP GEMM (K=1152)
  GemmDesc dm { h_bf, kaw_bf, h2, nullptr, 1152, 1024, 8, 256 };
  GemmDesc dz { nullptr, nullptr, nullptr, nullptr, 32, 128, 1, 0 };
  k_gemmx<<<dm.nb, 256, 0, stream>>>(dm, dz);

  // relu+bias -> LN -> dot -> sigmoid
  k_head<<<N_SEQ, 256, 0, stream>>>(h2, ka_b, ln_ka_g, ln_ka_b, kd_w, kd_b, out0);
}